// Round 20
// baseline (829.209 us; speedup 1.0000x reference)
//
#include <hip/hip_runtime.h>
#include <math.h>

#define OBSD   256
#define TSEQ   4096
#define NBATCH 32
#define DMODEL 128
#define DSTATE 64
#define DINNER 256
#define NHEADS 4
#define HEADDIM 64
#define NPROJ  644
#define NPPAD  768   // in_proj N padded to 6*128 (BN=128)
#define NTOK   (NBATCH*TSEQ)
#define CHUNK  64
#define NCHUNK (TSEQ/CHUNK)
#define NACT   64
#define BCW2   128   // bcbuf row width (B 64 | C 64)
#define LP     68    // padded LDS row stride (scan kernels)

typedef __attribute__((ext_vector_type(8))) short bf16x8;
typedef __attribute__((ext_vector_type(4))) float f32x4;
typedef __attribute__((ext_vector_type(8))) unsigned short u16x8;
typedef __attribute__((ext_vector_type(4))) unsigned short u16x4;

__device__ __forceinline__ float siluf(float x) { return x / (1.f + __expf(-x)); }

// round-to-nearest-even bf16 (bit pattern) and hi/lo split: v ~= hi + lo
__device__ __forceinline__ unsigned short bfhi(float v) {
    unsigned u = __float_as_uint(v);
    return (unsigned short)((u + 0x7FFFu + ((u >> 16) & 1u)) >> 16);
}
__device__ __forceinline__ void splitbf(float v, unsigned short& hi, unsigned short& lo) {
    hi = bfhi(v);
    const float hf = __uint_as_float((unsigned)hi << 16);
    lo = bfhi(v - hf);
}

// ---------------------------------------------------------------------------
// Split-bf16 MFMA GEMM (HW-verified round 10).
// SEG=1 (in_proj): BN=128 (r20) — one A-tile serves 128 cols, halving
//   A-staging VALU (in-register splitbf) and A re-fetch vs BN=64.
//   A staged from fp32 obs (r19), segmented epilogue.
// SEG=0 (logits): BN=64, bf16 A path (unchanged).
// Per-accumulator MFMA order unchanged -> bit-identical output.
// ---------------------------------------------------------------------------
template<int SEG>
__launch_bounds__(256)
__global__ void mfma_gemm(const float* __restrict__ Af32,
                          const unsigned short* __restrict__ Ahi,
                          const unsigned short* __restrict__ Alo,
                          const unsigned short* __restrict__ BThi,
                          const unsigned short* __restrict__ BTlo,
                          int K, const float* __restrict__ bias,
                          float* __restrict__ C,
                          float* __restrict__ zbuf, float* __restrict__ xbuf,
                          float* __restrict__ bcbuf, float* __restrict__ dtcol)
{
    constexpr int BN = (SEG == 1) ? 128 : 64;
    constexpr int NT = BN / 16;
    __shared__ __align__(16) unsigned short Ah[128][40], Al[128][40];
    __shared__ __align__(16) unsigned short Bh[BN][40],  Bl[BN][40];
    const int tid  = threadIdx.x;
    const int wave = tid >> 6, lane = tid & 63;
    const int l15 = lane & 15, l4 = lane >> 4;
    const int m0 = blockIdx.y * 128, n0 = blockIdx.x * BN;

    f32x4 acc[2][NT];
#pragma unroll
    for (int rt = 0; rt < 2; ++rt)
#pragma unroll
        for (int ct = 0; ct < NT; ++ct) acc[rt][ct] = (f32x4){0.f, 0.f, 0.f, 0.f};

    const int ar  = tid >> 1;           // A row 0..127
    const int akc = (tid & 1) * 16;     // k chunk base

    for (int k0 = 0; k0 < K; k0 += 32) {
        if constexpr (SEG == 1) {
            // stage A from fp32, split in-register (replaces conv_obs)
            const float* ap = Af32 + (size_t)(m0 + ar) * K + k0 + akc;
#pragma unroll
            for (int half = 0; half < 2; ++half) {
                const float4 v0 = *(const float4*)(ap + half * 8);
                const float4 v1 = *(const float4*)(ap + half * 8 + 4);
                const float va[8] = {v0.x, v0.y, v0.z, v0.w, v1.x, v1.y, v1.z, v1.w};
                u16x8 hh, ll;
#pragma unroll
                for (int e = 0; e < 8; ++e)
                    splitbf(va[e], ((unsigned short*)&hh)[e], ((unsigned short*)&ll)[e]);
                *(u16x8*)&Ah[ar][akc + half * 8] = hh;
                *(u16x8*)&Al[ar][akc + half * 8] = ll;
            }
            // stage B (pre-split bf16): 128 rows x 32 k, 2 vec8 per buffer
            const int br2  = tid >> 1;          // 0..127
            const int bkc2 = (tid & 1) * 16;
            const size_t bb = (size_t)(n0 + br2) * K + k0 + bkc2;
            *(u16x8*)&Bh[br2][bkc2]     = *(const u16x8*)(BThi + bb);
            *(u16x8*)&Bh[br2][bkc2 + 8] = *(const u16x8*)(BThi + bb + 8);
            *(u16x8*)&Bl[br2][bkc2]     = *(const u16x8*)(BTlo + bb);
            *(u16x8*)&Bl[br2][bkc2 + 8] = *(const u16x8*)(BTlo + bb + 8);
        } else {
            const size_t ab = (size_t)(m0 + ar) * K + k0 + akc;
            *(u16x8*)&Ah[ar][akc]     = *(const u16x8*)(Ahi + ab);
            *(u16x8*)&Ah[ar][akc + 8] = *(const u16x8*)(Ahi + ab + 8);
            *(u16x8*)&Al[ar][akc]     = *(const u16x8*)(Alo + ab);
            *(u16x8*)&Al[ar][akc + 8] = *(const u16x8*)(Alo + ab + 8);
            const int br  = tid >> 2;
            const int bkc = (tid & 3) * 8;
            const size_t bb = (size_t)(n0 + br) * K + k0 + bkc;
            *(u16x8*)&Bh[br][bkc] = *(const u16x8*)(BThi + bb);
            *(u16x8*)&Bl[br][bkc] = *(const u16x8*)(BTlo + bb);
        }
        __syncthreads();

        const int kk = l4 * 8;
        bf16x8 ah[2], al[2];
#pragma unroll
        for (int rt = 0; rt < 2; ++rt) {
            const int r = wave * 32 + rt * 16 + l15;
            ah[rt] = *(const bf16x8*)&Ah[r][kk];
            al[rt] = *(const bf16x8*)&Al[r][kk];
        }
#pragma unroll
        for (int ct = 0; ct < NT; ++ct) {
            const int n = ct * 16 + l15;
            const bf16x8 bh = *(const bf16x8*)&Bh[n][kk];
            const bf16x8 bl = *(const bf16x8*)&Bl[n][kk];
#pragma unroll
            for (int rt = 0; rt < 2; ++rt) {
                acc[rt][ct] = __builtin_amdgcn_mfma_f32_16x16x32_bf16(ah[rt], bh, acc[rt][ct], 0, 0, 0);
                acc[rt][ct] = __builtin_amdgcn_mfma_f32_16x16x32_bf16(ah[rt], bl, acc[rt][ct], 0, 0, 0);
                acc[rt][ct] = __builtin_amdgcn_mfma_f32_16x16x32_bf16(al[rt], bh, acc[rt][ct], 0, 0, 0);
            }
        }
        __syncthreads();
    }

#pragma unroll
    for (int rt = 0; rt < 2; ++rt) {
        const int rbase = m0 + wave * 32 + rt * 16 + l4 * 4;
#pragma unroll
        for (int ct = 0; ct < NT; ++ct) {
            const int cg = n0 + ct * 16 + l15;
            const float bv = bias[cg];
#pragma unroll
            for (int j = 0; j < 4; ++j) {
                const float v = acc[rt][ct][j] + bv;
                const size_t r = (size_t)(rbase + j);
                if constexpr (SEG == 0) {
                    C[r * NACT + cg] = v;
                } else {
                    if (cg < 256)      zbuf[r * DINNER + cg] = v;
                    else if (cg < 512) xbuf[r * DINNER + (cg - 256)] = v;
                    else if (cg < 640) bcbuf[r * BCW2 + (cg - 512)] = v;
                    else if (cg < NPROJ) dtcol[r * 4 + (cg - 640)] = v;
                }
            }
        }
    }
}

// ---------------------------------------------------------------------------
__global__ void make_wc(const float* __restrict__ W_enc, const float* __restrict__ W_in,
                        const float* __restrict__ b_enc,
                        unsigned short* __restrict__ WcThi, unsigned short* __restrict__ WcTlo,
                        float* __restrict__ bz)
{
    const int n = blockIdx.x;      // 0..NPPAD-1
    const int r = threadIdx.x;
    float v = 0.f;
    if (n < NPROJ)
        for (int k = 0; k < DMODEL; ++k)
            v = fmaf(W_enc[r * DMODEL + k], W_in[k * NPROJ + n], v);
    unsigned short hi, lo; splitbf(v, hi, lo);
    WcThi[n * OBSD + r] = hi;
    WcTlo[n * OBSD + r] = lo;
    if (r == 0) {
        float bv = 0.f;
        if (n < NPROJ)
            for (int k = 0; k < DMODEL; ++k)
                bv = fmaf(b_enc[k], W_in[k * NPROJ + n], bv);
        bz[n] = bv;
    }
}

// ---------------------------------------------------------------------------
__global__ void fuse_whead(const float* __restrict__ W_out, const float* __restrict__ W_act,
                           const float* __restrict__ W_val, const float* __restrict__ norm_w,
                           unsigned short* __restrict__ WhThi, unsigned short* __restrict__ WhTlo,
                           float* __restrict__ Wv)
{
    const int k = blockIdx.x;
    const int j = threadIdx.x;
    float s = 0.f;
    for (int m = 0; m < DMODEL; ++m)
        s = fmaf(W_out[k * DMODEL + m], W_act[m * NACT + j], s);
    s *= norm_w[k];
    unsigned short hi, lo; splitbf(s, hi, lo);
    WhThi[j * DINNER + k] = hi;
    WhTlo[j * DINNER + k] = lo;
    if (j == 0) {
        float sv = 0.f;
        for (int m = 0; m < DMODEL; ++m)
            sv = fmaf(W_out[k * DMODEL + m], W_val[m], sv);
        Wv[k] = sv * norm_w[k];
    }
}

// ---------------------------------------------------------------------------
__global__ void prep_scan(const float* __restrict__ dtcol, const float* __restrict__ dt_bias,
                          const float* __restrict__ A_log,
                          float* __restrict__ dtT, float* __restrict__ laT,
                          float* __restrict__ dApbuf)
{
    const int bc = blockIdx.x;
    const int bh = bc >> 6, c = bc & 63;
    const int b = bh >> 2, h = bh & 3;
    const int lane = threadIdx.x;
    const size_t tok = (size_t)b * TSEQ + c * CHUNK + lane;
    const float x = dtcol[tok * 4 + h] + dt_bias[h];
    const float dt = (x > 20.f) ? x : log1pf(expf(x));
    const float A = -expf(A_log[h]);
    float v = dt * A;
#pragma unroll
    for (int d = 1; d < 64; d <<= 1) {
        const float o = __shfl_up(v, d, 64);
        if (lane >= d) v += o;
    }
    const size_t o = (size_t)bh * TSEQ + c * CHUNK + lane;
    dtT[o] = dt;
    laT[o] = v;
    if (lane == 63) dApbuf[bh * NCHUNK + c] = __expf(v);
}

// ---------------------------------------------------------------------------
// Phase A: chunk-local states via GEMM (fp32 VALU — passed r9..r19).
// ---------------------------------------------------------------------------
__launch_bounds__(256)
__global__ void scan_state(const float* __restrict__ xbuf, const float* __restrict__ bcbuf,
                           const float* __restrict__ dtT, const float* __restrict__ laT,
                           const float* __restrict__ W_conv, const float* __restrict__ b_conv,
                           float* __restrict__ states)
{
    __shared__ float Xs[CHUNK][LP];
    __shared__ float Bw[CHUNK][LP];
    __shared__ float w_l[CHUNK];
    const int c = blockIdx.x, bh = blockIdx.y;
    const int b = bh >> 2, h = bh & 3;
    const int tid = threadIdx.x;
    const size_t row0 = (size_t)b * TSEQ;
    const int tb = c * CHUNK;

    if (tid < CHUNK) {
        const size_t o = (size_t)bh * TSEQ + tb;
        const float laLast = laT[o + CHUNK - 1];
        w_l[tid] = dtT[o + tid] * __expf(laLast - laT[o + tid]);
    }
    __syncthreads();

    const int sg = tid & 15, st = tid >> 4;
    const int t4 = st * 4;

    {
        const int ch = h * HEADDIM + sg * 4;
        float w[4][4], bb[4];
#pragma unroll
        for (int j = 0; j < 4; ++j) {
            bb[j] = b_conv[ch + j];
#pragma unroll
            for (int k = 0; k < 4; ++k) w[j][k] = W_conv[(ch + j) * 4 + k];
        }
        float rx[4][7];
#pragma unroll
        for (int r = 0; r < 7; ++r) {
            const int tg = tb + t4 - 3 + r;
            float4 v = make_float4(0.f, 0.f, 0.f, 0.f);
            if (tg >= 0) v = *(const float4*)(xbuf + (row0 + tg) * DINNER + ch);
            rx[0][r] = v.x; rx[1][r] = v.y; rx[2][r] = v.z; rx[3][r] = v.w;
        }
#pragma unroll
        for (int i = 0; i < 4; ++i) {
            float o[4];
#pragma unroll
            for (int j = 0; j < 4; ++j)
                o[j] = siluf(fmaf(rx[j][i + 3], w[j][3], fmaf(rx[j][i + 2], w[j][2],
                             fmaf(rx[j][i + 1], w[j][1], fmaf(rx[j][i], w[j][0], bb[j])))));
            *(float4*)&Xs[t4 + i][sg * 4] = make_float4(o[0], o[1], o[2], o[3]);
        }
    }
    {
        const int ch = sg * 4;
        float w[4][4], bb[4];
#pragma unroll
        for (int j = 0; j < 4; ++j) {
            bb[j] = b_conv[DINNER + ch + j];
#pragma unroll
            for (int k = 0; k < 4; ++k) w[j][k] = W_conv[(DINNER + ch + j) * 4 + k];
        }
        float rx[4][7];
#pragma unroll
        for (int r = 0; r < 7; ++r) {
            const int tg = tb + t4 - 3 + r;
            float4 v = make_float4(0.f, 0.f, 0.f, 0.f);
            if (tg >= 0) v = *(const float4*)(bcbuf + (row0 + tg) * BCW2 + ch);
            rx[0][r] = v.x; rx[1][r] = v.y; rx[2][r] = v.z; rx[3][r] = v.w;
        }
#pragma unroll
        for (int i = 0; i < 4; ++i) {
            const float wi = w_l[t4 + i];
            float o[4];
#pragma unroll
            for (int j = 0; j < 4; ++j)
                o[j] = wi * siluf(fmaf(rx[j][i + 3], w[j][3], fmaf(rx[j][i + 2], w[j][2],
                              fmaf(rx[j][i + 1], w[j][1], fmaf(rx[j][i], w[j][0], bb[j])))));
            *(float4*)&Bw[t4 + i][sg * 4] = make_float4(o[0], o[1], o[2], o[3]);
        }
    }
    __syncthreads();

    const int pn = tid & 15, pp = tid >> 4;
    const int n4 = pn * 4, p4 = pp * 4;
    float acc[4][4];
#pragma unroll
    for (int a = 0; a < 4; ++a)
#pragma unroll
        for (int d = 0; d < 4; ++d) acc[a][d] = 0.f;
#pragma unroll 4
    for (int i = 0; i < CHUNK; ++i) {
        const float4 xv = *(const float4*)&Xs[i][p4];
        const float4 bv = *(const float4*)&Bw[i][n4];
        const float xa[4] = {xv.x, xv.y, xv.z, xv.w};
        const float ba[4] = {bv.x, bv.y, bv.z, bv.w};
#pragma unroll
        for (int a = 0; a < 4; ++a)
#pragma unroll
            for (int d = 0; d < 4; ++d) acc[a][d] = fmaf(xa[a], ba[d], acc[a][d]);
    }
    const size_t so = (size_t)(bh * NCHUNK + c) * 4096;
#pragma unroll
    for (int a = 0; a < 4; ++a)
        *(float4*)(states + so + (size_t)(p4 + a) * 64 + n4) =
            make_float4(acc[a][0], acc[a][1], acc[a][2], acc[a][3]);
}

// ---------------------------------------------------------------------------
__global__ void chunk_scan(float* __restrict__ states, const float* __restrict__ dAprod)
{
    __shared__ float sdA[NCHUNK];
    const int bh = blockIdx.x >> 4;
    const int elem = ((blockIdx.x & 15) << 8) | threadIdx.x;
    if (threadIdx.x < NCHUNK) sdA[threadIdx.x] = dAprod[bh * NCHUNK + threadIdx.x];
    __syncthreads();
    const size_t base = (size_t)bh * NCHUNK * 4096 + elem;
    float s0 = 0.f;
    for (int c = 0; c < NCHUNK; ++c) {
        const size_t off = base + (size_t)c * 4096;
        const float Sc = states[off];
        states[off] = s0;
        s0 = fmaf(sdA[c], s0, Sc);
    }
}

// ---------------------------------------------------------------------------
// Phase B: outputs via 3 fp32 micro-GEMMs per (bh, chunk).
// 2-slot LDS (36 KB): Slot P = BcT -> ST -> Xs ; Slot Q = CcT -> MT (r18).
// ---------------------------------------------------------------------------
__launch_bounds__(256)
__global__ void scan_out(const float* __restrict__ xbuf, const float* __restrict__ bcbuf,
                         float* zbuf,
                         const float* __restrict__ dtT, const float* __restrict__ laT,
                         const float* __restrict__ W_conv, const float* __restrict__ b_conv,
                         const float* __restrict__ Dparam,
                         const float* __restrict__ states)
{
    __shared__ float BcT[CHUNK][LP];   // P: Bc[n][i] -> ST[n][p] -> Xs[t][p]
    __shared__ float CcT[CHUNK][LP];   // Q: Cc[n][t] -> MT[i][t]
    __shared__ float la_l[CHUNK], dt_l[CHUNK], a_l[CHUNK];
    float (*ST)[LP] = BcT;
    float (*MT)[LP] = CcT;
    float (*Xs)[LP] = BcT;             // staged after GEMM3 (ST dead)

    const int c = blockIdx.x, bh = blockIdx.y;
    const int b = bh >> 2, h = bh & 3;
    const int tid = threadIdx.x;
    const size_t row0 = (size_t)b * TSEQ;
    const int tb = c * CHUNK;
    const float Dh = Dparam[h];

    const int pS = tid >> 2;
    const int n16 = (tid & 3) * 16;
    const float* Sg = states + (size_t)(bh * NCHUNK + c) * 4096 + (size_t)pS * 64 + n16;
    const float4 sv0 = *(const float4*)(Sg + 0);
    const float4 sv1 = *(const float4*)(Sg + 4);
    const float4 sv2 = *(const float4*)(Sg + 8);
    const float4 sv3 = *(const float4*)(Sg + 12);

    if (tid < CHUNK) {
        const size_t o = (size_t)bh * TSEQ + tb + tid;
        const float la = laT[o];
        la_l[tid] = la;
        dt_l[tid] = dtT[o];
        a_l[tid] = __expf(la);
    }

    const int sg = tid & 15, st = tid >> 4;
    const int t4s = st * 4;

    {   // B -> BcT[n][i] (transposed store)
        const int ch = sg * 4;
        float w[4][4], bb[4];
#pragma unroll
        for (int j = 0; j < 4; ++j) {
            bb[j] = b_conv[DINNER + ch + j];
#pragma unroll
            for (int k = 0; k < 4; ++k) w[j][k] = W_conv[(DINNER + ch + j) * 4 + k];
        }
        float rx[4][7];
#pragma unroll
        for (int r = 0; r < 7; ++r) {
            const int tg = tb + t4s - 3 + r;
            float4 v = make_float4(0.f, 0.f, 0.f, 0.f);
            if (tg >= 0) v = *(const float4*)(bcbuf + (row0 + tg) * BCW2 + ch);
            rx[0][r] = v.x; rx[1][r] = v.y; rx[2][r] = v.z; rx[3][r] = v.w;
        }
#pragma unroll
        for (int j = 0; j < 4; ++j) {
            float o[4];
#pragma unroll
            for (int i = 0; i < 4; ++i)
                o[i] = siluf(fmaf(rx[j][i + 3], w[j][3], fmaf(rx[j][i + 2], w[j][2],
                             fmaf(rx[j][i + 1], w[j][1], fmaf(rx[j][i], w[j][0], bb[j])))));
            *(float4*)&BcT[ch + j][t4s] = make_float4(o[0], o[1], o[2], o[3]);
        }
    }
    {   // C -> CcT[n][t] (transposed store)
        const int ch = sg * 4;
        float w[4][4], bb[4];
#pragma unroll
        for (int j = 0; j < 4; ++j) {
            bb[j] = b_conv[DINNER + 64 + ch + j];
#pragma unroll
            for (int k = 0; k < 4; ++k) w[j][k] = W_conv[(DINNER + 64 + ch + j) * 4 + k];
        }
        float rx[4][7];
#pragma unroll
        for (int r = 0; r < 7; ++r) {
            const int tg = tb + t4s - 3 + r;
            float4 v = make_float4(0.f, 0.f, 0.f, 0.f);
            if (tg >= 0) v = *(const float4*)(bcbuf + (row0 + tg) * BCW2 + 64 + ch);
            rx[0][r] = v.x; rx[1][r] = v.y; rx[2][r] = v.z; rx[3][r] = v.w;
        }
#pragma unroll
        for (int j = 0; j < 4; ++j) {
            float o[4];
#pragma unroll
            for (int i = 0; i < 4; ++i)
                o[i] = siluf(fmaf(rx[j][i + 3], w[j][3], fmaf(rx[j][i + 2], w[j][2],
                             fmaf(rx[j][i + 1], w[j][1], fmaf(rx[j][i], w[j][0], bb[j])))));
            *(float4*)&CcT[ch + j][t4s] = make_float4(o[0], o[1], o[2], o[3]);
        }
    }
    __syncthreads();

    const int ti = tid & 15, tt = tid >> 4;
    const int i4 = ti * 4, t4 = tt * 4;

    // ---- GEMM1: M0[t][i] = C.B^T ----
    float m[4][4];
#pragma unroll
    for (int a = 0; a < 4; ++a)
#pragma unroll
        for (int d = 0; d < 4; ++d) m[a][d] = 0.f;
#pragma unroll 4
    for (int n = 0; n < 64; ++n) {
        const float4 cv = *(const float4*)&CcT[n][t4];
        const float4 bv = *(const float4*)&BcT[n][i4];
        const float ca[4] = {cv.x, cv.y, cv.z, cv.w};
        const float ba[4] = {bv.x, bv.y, bv.z, bv.w};
#pragma unroll
        for (int a = 0; a < 4; ++a)
#pragma unroll
            for (int d = 0; d < 4; ++d) m[a][d] = fmaf(ca[a], ba[d], m[a][d]);
    }
    // decay + causal mask (mask BEFORE exp)
    {
        float lat[4], lai[4], dti[4];
#pragma unroll
        for (int a = 0; a < 4; ++a) lat[a] = la_l[t4 + a];
#pragma unroll
        for (int d = 0; d < 4; ++d) { lai[d] = la_l[i4 + d]; dti[d] = dt_l[i4 + d]; }
#pragma unroll
        for (int a = 0; a < 4; ++a)
#pragma unroll
            for (int d = 0; d < 4; ++d) {
                if (i4 + d <= t4 + a)
                    m[a][d] = m[a][d] * dti[d] * __expf(lat[a] - lai[d]);
                else
                    m[a][d] = 0.f;
            }
    }
    __syncthreads();   // all waves done reading BcT

    // ---- ST[n][p] = S_old[p][n] (slot P) ----
    {
        const float sa[16] = {sv0.x, sv0.y, sv0.z, sv0.w, sv1.x, sv1.y, sv1.z, sv1.w,
                              sv2.x, sv2.y, sv2.z, sv2.w, sv3.x, sv3.y, sv3.z, sv3.w};
#pragma unroll
        for (int q = 0; q < 16; ++q) ST[n16 + q][pS] = sa[q];
    }
    __syncthreads();

    // ---- GEMM3: Y2[t][p] = C.S^T ----
    float y2[4][4];
#pragma unroll
    for (int a = 0; a < 4; ++a)
#pragma unroll
        for (int d = 0; d < 4; ++d) y2[a][d] = 0.f;
#pragma unroll 4
    for (int n = 0; n < 64; ++n) {
        const float4 cv = *(const float4*)&CcT[n][t4];
        const float4 sv = *(const float4*)&ST[n][i4];
        const float ca[4] = {cv.x, cv.y, cv.z, cv.w};
        const float sa[4] = {sv.x, sv.y, sv.z, sv.w};
#pragma unroll
        for (int a = 0; a < 4; ++a)
#pragma unroll
            for (int d = 0; d < 4; ++d) y2[a][d] = fmaf(ca[a], sa[d], y2[a][d]);
    }
    __syncthreads();   // GEMM3 done: ST (slot P) and Cc (slot Q) both dead

    // ---- MT[i][t] = M[t][i] (slot Q)  +  Xs[t][p] staging (slot P) ----
#pragma unroll
    for (int d = 0; d < 4; ++d)
        *(float4*)&MT[i4 + d][t4] = make_float4(m[0][d], m[1][d], m[2][d], m[3][d]);
    {   // X -> Xs[t][p]: conv+silu of x, this head's 64 channels
        const int ch = h * HEADDIM + sg * 4;
        float w[4][4], bb[4];
#pragma unroll
        for (int j = 0; j < 4; ++j) {
            bb[j] = b_conv[ch + j];
#pragma unroll
            for (int k = 0; k < 4; ++k) w[j][k] = W_conv[(ch + j) * 4 + k];
        }
        float rx[4][7];
#pragma unroll
        for (int r = 0; r < 7; ++r) {
            const int tg = tb + t4s - 3 + r;
            float4 v = make_float4(0.f, 0.f, 0.f, 0.f);
            if (tg >= 0) v = *(const float4*)(xbuf + (row0 + tg) * DINNER + ch);
            rx[0][r] = v.x; rx[1][r] = v.y; rx[2][r] = v.z; rx[3][r] = v.w;
        }
#pragma unroll
        for (int i = 0; i < 4; ++i) {
            float o[4];
#pragma unroll
            for (int j = 0; j < 4; ++j)
                o[j] = siluf(fmaf(rx[j][i + 3], w[j][3], fmaf(rx[j][i + 2], w[j][2],
                             fmaf(rx[j][i + 1], w[j][1], fmaf(rx[j][i], w[j][0], bb[j])))));
            *(float4*)&Xs[t4s + i][sg * 4] = make_float4(o[0], o[1], o[2], o[3]);
        }
    }
    __syncthreads();

    // ---- GEMM2: Yac[t][p] = M.X ----
    float yac[4][4];
#pragma unroll
    for (int a = 0; a < 4; ++a)
#pragma unroll
        for (int d = 0; d < 4; ++d) yac[a][d] = 0.f;
#pragma unroll 4
    for (int k = 0; k < CHUNK; ++k) {
        const float4 mv = *(const float4*)&MT[k][t4];
        const float4 xv = *(const float4*)&Xs[k][i4];
        const float ma[4] = {mv.x, mv.y, mv.z, mv.w};
        const float xa[4] = {xv.x, xv.y, xv.z, xv.w};
#pragma unroll
        for (int a = 0; a < 4; ++a)
#pragma unroll
            for (int d = 0; d < 4; ++d) yac[a][d] = fmaf(ma[a], xa[d], yac[a][d]);
    }

    // ---- epilogue: Y = Yac + a[t]*Y2 + D*X ; g = Y*silu(z) -> zbuf ----
#pragma unroll
    for (int a = 0; a < 4; ++a) {
        const int t = t4 + a;
        const float at = a_l[t];
        const float4 xv = *(const float4*)&Xs[t][i4];
        const float xa[4] = {xv.x, xv.y, xv.z, xv.w};
        float* zp = zbuf + (row0 + tb + t) * DINNER + h * HEADDIM + i4;
        const float4 zv = *(const float4*)zp;
        const float za[4] = {zv.x, zv.y, zv.z, zv.w};
        float g[4];
#pragma unroll
        for (int d = 0; d < 4; ++d) {
            const float Y = yac[a][d] + at * y2[a][d] + Dh * xa[d];
            g[d] = Y * siluf(za[d]);
        }
        *(float4*)zp = make_float4(g[0], g[1], g[2], g[3]);
    }
}

// ---------------------------------------------------------------------------
__launch_bounds__(256)
__global__ void rms_val(const float* __restrict__ g, const float* __restrict__ Wv,
                        const float* __restrict__ bval, float* __restrict__ values,
                        unsigned short* __restrict__ Ghi, unsigned short* __restrict__ Glo)
{
    const size_t tok = (size_t)blockIdx.x * 4 + (threadIdx.x >> 6);
    const int lane = threadIdx.x & 63;
    const float4 v = *(const float4*)(g + tok * DINNER + lane * 4);
    const float4 w = *(const float4*)(Wv + lane * 4);
    float ssq = v.x * v.x + v.y * v.y + v.z * v.z + v.w * v.w;
    float gw  = v.x * w.x + v.y * w.y + v.z * w.z + v.w * w.w;
#pragma unroll
    for (int d = 1; d < 64; d <<= 1) {
        ssq += __shfl_xor(ssq, d, 64);
        gw  += __shfl_xor(gw, d, 64);
    }
    const float rms = rsqrtf(ssq * (1.f / DINNER) + 1e-5f);
    u16x4 h, l;
    splitbf(v.x * rms, ((unsigned short*)&h)[0], ((unsigned short*)&l)[0]);
    splitbf(v.y * rms, ((unsigned short*)&h)[1], ((unsigned short*)&l)[1]);
    splitbf(v.z * rms, ((unsigned short*)&h)[2], ((unsigned short*)&l)[2]);
    splitbf(v.w * rms, ((unsigned short*)&h)[3], ((unsigned short*)&l)[3]);
    *(u16x4*)(Ghi + tok * DINNER + lane * 4) = h;
    *(u16x4*)(Glo + tok * DINNER + lane * 4) = l;
    if (lane == 0) values[tok] = gw * rms + bval[0];
}

// ---------------------------------------------------------------------------
extern "C" void kernel_launch(void* const* d_in, const int* in_sizes, int n_in,
                              void* d_out, int out_size, void* d_ws, size_t ws_size,
                              hipStream_t stream)
{
    (void)in_sizes; (void)n_in; (void)out_size; (void)ws_size;
    const float* obs     = (const float*)d_in[0];
    const float* W_enc   = (const float*)d_in[1];
    const float* b_enc   = (const float*)d_in[2];
    const float* W_in    = (const float*)d_in[3];
    const float* W_conv  = (const float*)d_in[4];
    const float* b_conv  = (const float*)d_in[5];
    const float* dt_bias = (const float*)d_in[6];
    const float* A_log   = (const float*)d_in[7];
    const float* Dp      = (const float*)d_in[8];
    const float* norm_w  = (const float*)d_in[9];
    const float* W_out   = (const float*)d_in[10];
    const float* W_act   = (const float*)d_in[11];
    const float* b_act   = (const float*)d_in[12];
    const float* W_val   = (const float*)d_in[13];
    const float* b_val   = (const float*)d_in[14];

    float* logits = (float*)d_out;
    float* values = logits + (size_t)NTOK * NACT;

    char* ws = (char*)d_ws;
    size_t off = 0;
    auto alloc = [&](size_t nbytes) {
        char* ptr = ws + off;
        off += (nbytes + 255) / 256 * 256;
        return ptr;
    };
    float* zbuf   = (float*)alloc((size_t)NTOK * DINNER * 4);   // z -> g in place
    float* xbuf   = (float*)alloc((size_t)NTOK * DINNER * 4);
    float* bcbuf  = (float*)alloc((size_t)NTOK * BCW2 * 4);
    float* dtcol  = (float*)alloc((size_t)NTOK * 4 * 4);
    // shared 134.2 MB region: states (scan) -> g-bf16 (rms_val/logits)
    char*  shared = alloc((size_t)NTOK * OBSD * 2 * 2);
    float* states = (float*)shared;
    unsigned short* Ghi = (unsigned short*)shared;
    unsigned short* Glo = Ghi + (size_t)NTOK * DINNER;
    float* dtT    = (float*)alloc((size_t)NBATCH * NHEADS * TSEQ * 4);
    float* laT    = (float*)alloc((size_t)NBATCH * NHEADS * TSEQ * 4);
    float* dApb   = (float*)alloc(NBATCH * NHEADS * NCHUNK * 4);
    unsigned short* WcThi = (unsigned short*)alloc((size_t)NPPAD * OBSD * 2);
    unsigned short* WcTlo = (unsigned short*)alloc((size_t)NPPAD * OBSD * 2);
    float* bz     = (float*)alloc(NPPAD * 4);
    unsigned short* WhThi = (unsigned short*)alloc((size_t)NACT * DINNER * 2);
    unsigned short* WhTlo = (unsigned short*)alloc((size_t)NACT * DINNER * 2);
    float* Wv     = (float*)alloc(DINNER * 4);

    fuse_whead<<<DINNER, NACT, 0, stream>>>(W_out, W_act, W_val, norm_w, WhThi, WhTlo, Wv);
    make_wc<<<NPPAD, 256, 0, stream>>>(W_enc, W_in, b_enc, WcThi, WcTlo, bz);
    // in_proj: BN=128, A staged from fp32 obs, split in-register
    mfma_gemm<1><<<dim3(NPPAD / 128, NTOK / 128), 256, 0, stream>>>(
        obs, nullptr, nullptr, WcThi, WcTlo, OBSD, bz, nullptr, zbuf, xbuf, bcbuf, dtcol);
    prep_scan<<<NBATCH * NHEADS * NCHUNK, 64, 0, stream>>>(
        dtcol, dt_bias, A_log, dtT, laT, dApb);
    scan_state<<<dim3(NCHUNK, NBATCH * NHEADS), 256, 0, stream>>>(
        xbuf, bcbuf, dtT, laT, W_conv, b_conv, states);
    chunk_scan<<<NBATCH * NHEADS * 16, 256, 0, stream>>>(states, dApb);
    scan_out<<<dim3(NCHUNK, NBATCH * NHEADS), 256, 0, stream>>>(
        xbuf, bcbuf, zbuf, dtT, laT, W_conv, b_conv, Dp, states);
    rms_val<<<NTOK / 4, 256, 0, stream>>>(zbuf, Wv, b_val, values, Ghi, Glo);
    mfma_gemm<0><<<dim3(1, NTOK / 128), 256, 0, stream>>>(
        nullptr, Ghi, Glo, WhThi, WhTlo, DINNER, b_act, logits, nullptr, nullptr, nullptr, nullptr);
}

// Round 21
// 801.929 us; speedup vs baseline: 1.0340x; 1.0340x over previous
//
#include <hip/hip_runtime.h>
#include <math.h>

#define OBSD   256
#define TSEQ   4096
#define NBATCH 32
#define DMODEL 128
#define DSTATE 64
#define DINNER 256
#define NHEADS 4
#define HEADDIM 64
#define NPROJ  644
#define NPPAD  704   // in_proj N padded to 11*64
#define NTOK   (NBATCH*TSEQ)
#define CHUNK  64
#define NCHUNK (TSEQ/CHUNK)
#define NACT   64
#define BCW2   128   // bcbuf row width (B 64 | C 64)
#define LP     68    // padded LDS row stride (scan kernels)

typedef __attribute__((ext_vector_type(8))) short bf16x8;
typedef __attribute__((ext_vector_type(4))) float f32x4;
typedef __attribute__((ext_vector_type(8))) unsigned short u16x8;
typedef __attribute__((ext_vector_type(4))) unsigned short u16x4;

__device__ __forceinline__ float siluf(float x) { return x / (1.f + __expf(-x)); }

// round-to-nearest-even bf16 (bit pattern) and hi/lo split: v ~= hi + lo
__device__ __forceinline__ unsigned short bfhi(float v) {
    unsigned u = __float_as_uint(v);
    return (unsigned short)((u + 0x7FFFu + ((u >> 16) & 1u)) >> 16);
}
__device__ __forceinline__ void splitbf(float v, unsigned short& hi, unsigned short& lo) {
    hi = bfhi(v);
    const float hf = __uint_as_float((unsigned)hi << 16);
    lo = bfhi(v - hf);
}

// ---------------------------------------------------------------------------
// Split-bf16 MFMA GEMM (HW-verified round 10).
// SEG=1 stages A directly from fp32 (obs), splitting to bf16 hi/lo
// in-register (r19 — deletes conv_obs). SEG=0 keeps bf16 A path.
// ---------------------------------------------------------------------------
template<int SEG>
__launch_bounds__(256)
__global__ void mfma_gemm(const float* __restrict__ Af32,
                          const unsigned short* __restrict__ Ahi,
                          const unsigned short* __restrict__ Alo,
                          const unsigned short* __restrict__ BThi,
                          const unsigned short* __restrict__ BTlo,
                          int K, const float* __restrict__ bias,
                          float* __restrict__ C,
                          float* __restrict__ zbuf, float* __restrict__ xbuf,
                          float* __restrict__ bcbuf, float* __restrict__ dtcol)
{
    __shared__ __align__(16) unsigned short Ah[128][40], Al[128][40];
    __shared__ __align__(16) unsigned short Bh[64][40],  Bl[64][40];
    const int tid  = threadIdx.x;
    const int wave = tid >> 6, lane = tid & 63;
    const int l15 = lane & 15, l4 = lane >> 4;
    const int m0 = blockIdx.y * 128, n0 = blockIdx.x * 64;

    f32x4 acc[2][4];
#pragma unroll
    for (int rt = 0; rt < 2; ++rt)
#pragma unroll
        for (int ct = 0; ct < 4; ++ct) acc[rt][ct] = (f32x4){0.f, 0.f, 0.f, 0.f};

    const int ar  = tid >> 1;           // A row 0..127
    const int akc = (tid & 1) * 16;     // k chunk base
    const int br  = tid >> 2;           // B row (n)
    const int bkc = (tid & 3) * 8;

    for (int k0 = 0; k0 < K; k0 += 32) {
        if constexpr (SEG == 1) {
            // stage A from fp32, split in-register (replaces conv_obs)
            const float* ap = Af32 + (size_t)(m0 + ar) * K + k0 + akc;
#pragma unroll
            for (int half = 0; half < 2; ++half) {
                const float4 v0 = *(const float4*)(ap + half * 8);
                const float4 v1 = *(const float4*)(ap + half * 8 + 4);
                const float va[8] = {v0.x, v0.y, v0.z, v0.w, v1.x, v1.y, v1.z, v1.w};
                u16x8 hh, ll;
#pragma unroll
                for (int e = 0; e < 8; ++e)
                    splitbf(va[e], ((unsigned short*)&hh)[e], ((unsigned short*)&ll)[e]);
                *(u16x8*)&Ah[ar][akc + half * 8] = hh;
                *(u16x8*)&Al[ar][akc + half * 8] = ll;
            }
        } else {
            const size_t ab = (size_t)(m0 + ar) * K + k0 + akc;
            *(u16x8*)&Ah[ar][akc]     = *(const u16x8*)(Ahi + ab);
            *(u16x8*)&Ah[ar][akc + 8] = *(const u16x8*)(Ahi + ab + 8);
            *(u16x8*)&Al[ar][akc]     = *(const u16x8*)(Alo + ab);
            *(u16x8*)&Al[ar][akc + 8] = *(const u16x8*)(Alo + ab + 8);
        }
        {
            const size_t bb = (size_t)(n0 + br) * K + k0 + bkc;
            *(u16x8*)&Bh[br][bkc] = *(const u16x8*)(BThi + bb);
            *(u16x8*)&Bl[br][bkc] = *(const u16x8*)(BTlo + bb);
        }
        __syncthreads();

        const int kk = l4 * 8;
        bf16x8 ah[2], al[2], bh[4], bl[4];
#pragma unroll
        for (int rt = 0; rt < 2; ++rt) {
            const int r = wave * 32 + rt * 16 + l15;
            ah[rt] = *(const bf16x8*)&Ah[r][kk];
            al[rt] = *(const bf16x8*)&Al[r][kk];
        }
#pragma unroll
        for (int ct = 0; ct < 4; ++ct) {
            const int n = ct * 16 + l15;
            bh[ct] = *(const bf16x8*)&Bh[n][kk];
            bl[ct] = *(const bf16x8*)&Bl[n][kk];
        }
#pragma unroll
        for (int rt = 0; rt < 2; ++rt)
#pragma unroll
            for (int ct = 0; ct < 4; ++ct) {
                acc[rt][ct] = __builtin_amdgcn_mfma_f32_16x16x32_bf16(ah[rt], bh[ct], acc[rt][ct], 0, 0, 0);
                acc[rt][ct] = __builtin_amdgcn_mfma_f32_16x16x32_bf16(ah[rt], bl[ct], acc[rt][ct], 0, 0, 0);
                acc[rt][ct] = __builtin_amdgcn_mfma_f32_16x16x32_bf16(al[rt], bh[ct], acc[rt][ct], 0, 0, 0);
            }
        __syncthreads();
    }

#pragma unroll
    for (int rt = 0; rt < 2; ++rt) {
        const int rbase = m0 + wave * 32 + rt * 16 + l4 * 4;
#pragma unroll
        for (int ct = 0; ct < 4; ++ct) {
            const int cg = n0 + ct * 16 + l15;
            const float bv = bias[cg];
#pragma unroll
            for (int j = 0; j < 4; ++j) {
                const float v = acc[rt][ct][j] + bv;
                const size_t r = (size_t)(rbase + j);
                if constexpr (SEG == 0) {
                    C[r * NACT + cg] = v;
                } else {
                    if (cg < 256)      zbuf[r * DINNER + cg] = v;
                    else if (cg < 512) xbuf[r * DINNER + (cg - 256)] = v;
                    else if (cg < 640) bcbuf[r * BCW2 + (cg - 512)] = v;
                    else if (cg < NPROJ) dtcol[r * 4 + (cg - 640)] = v;
                }
            }
        }
    }
}

// ---------------------------------------------------------------------------
__global__ void make_wc(const float* __restrict__ W_enc, const float* __restrict__ W_in,
                        const float* __restrict__ b_enc,
                        unsigned short* __restrict__ WcThi, unsigned short* __restrict__ WcTlo,
                        float* __restrict__ bz)
{
    const int n = blockIdx.x;
    const int r = threadIdx.x;
    float v = 0.f;
    if (n < NPROJ)
        for (int k = 0; k < DMODEL; ++k)
            v = fmaf(W_enc[r * DMODEL + k], W_in[k * NPROJ + n], v);
    unsigned short hi, lo; splitbf(v, hi, lo);
    WcThi[n * OBSD + r] = hi;
    WcTlo[n * OBSD + r] = lo;
    if (r == 0) {
        float bv = 0.f;
        if (n < NPROJ)
            for (int k = 0; k < DMODEL; ++k)
                bv = fmaf(b_enc[k], W_in[k * NPROJ + n], bv);
        bz[n] = bv;
    }
}

// ---------------------------------------------------------------------------
__global__ void fuse_whead(const float* __restrict__ W_out, const float* __restrict__ W_act,
                           const float* __restrict__ W_val, const float* __restrict__ norm_w,
                           unsigned short* __restrict__ WhThi, unsigned short* __restrict__ WhTlo,
                           float* __restrict__ Wv)
{
    const int k = blockIdx.x;
    const int j = threadIdx.x;
    float s = 0.f;
    for (int m = 0; m < DMODEL; ++m)
        s = fmaf(W_out[k * DMODEL + m], W_act[m * NACT + j], s);
    s *= norm_w[k];
    unsigned short hi, lo; splitbf(s, hi, lo);
    WhThi[j * DINNER + k] = hi;
    WhTlo[j * DINNER + k] = lo;
    if (j == 0) {
        float sv = 0.f;
        for (int m = 0; m < DMODEL; ++m)
            sv = fmaf(W_out[k * DMODEL + m], W_val[m], sv);
        Wv[k] = sv * norm_w[k];
    }
}

// ---------------------------------------------------------------------------
__global__ void prep_scan(const float* __restrict__ dtcol, const float* __restrict__ dt_bias,
                          const float* __restrict__ A_log,
                          float* __restrict__ dtT, float* __restrict__ laT,
                          float* __restrict__ dApbuf)
{
    const int bc = blockIdx.x;
    const int bh = bc >> 6, c = bc & 63;
    const int b = bh >> 2, h = bh & 3;
    const int lane = threadIdx.x;
    const size_t tok = (size_t)b * TSEQ + c * CHUNK + lane;
    const float x = dtcol[tok * 4 + h] + dt_bias[h];
    const float dt = (x > 20.f) ? x : log1pf(expf(x));
    const float A = -expf(A_log[h]);
    float v = dt * A;
#pragma unroll
    for (int d = 1; d < 64; d <<= 1) {
        const float o = __shfl_up(v, d, 64);
        if (lane >= d) v += o;
    }
    const size_t o = (size_t)bh * TSEQ + c * CHUNK + lane;
    dtT[o] = dt;
    laT[o] = v;
    if (lane == 63) dApbuf[bh * NCHUNK + c] = __expf(v);
}

// ---------------------------------------------------------------------------
// Phase A: chunk-local states via GEMM (fp32 VALU — passed r9..r19).
// ---------------------------------------------------------------------------
__launch_bounds__(256)
__global__ void scan_state(const float* __restrict__ xbuf, const float* __restrict__ bcbuf,
                           const float* __restrict__ dtT, const float* __restrict__ laT,
                           const float* __restrict__ W_conv, const float* __restrict__ b_conv,
                           float* __restrict__ states)
{
    __shared__ float Xs[CHUNK][LP];
    __shared__ float Bw[CHUNK][LP];
    __shared__ float w_l[CHUNK];
    const int c = blockIdx.x, bh = blockIdx.y;
    const int b = bh >> 2, h = bh & 3;
    const int tid = threadIdx.x;
    const size_t row0 = (size_t)b * TSEQ;
    const int tb = c * CHUNK;

    if (tid < CHUNK) {
        const size_t o = (size_t)bh * TSEQ + tb;
        const float laLast = laT[o + CHUNK - 1];
        w_l[tid] = dtT[o + tid] * __expf(laLast - laT[o + tid]);
    }
    __syncthreads();

    const int sg = tid & 15, st = tid >> 4;
    const int t4 = st * 4;

    {
        const int ch = h * HEADDIM + sg * 4;
        float w[4][4], bb[4];
#pragma unroll
        for (int j = 0; j < 4; ++j) {
            bb[j] = b_conv[ch + j];
#pragma unroll
            for (int k = 0; k < 4; ++k) w[j][k] = W_conv[(ch + j) * 4 + k];
        }
        float rx[4][7];
#pragma unroll
        for (int r = 0; r < 7; ++r) {
            const int tg = tb + t4 - 3 + r;
            float4 v = make_float4(0.f, 0.f, 0.f, 0.f);
            if (tg >= 0) v = *(const float4*)(xbuf + (row0 + tg) * DINNER + ch);
            rx[0][r] = v.x; rx[1][r] = v.y; rx[2][r] = v.z; rx[3][r] = v.w;
        }
#pragma unroll
        for (int i = 0; i < 4; ++i) {
            float o[4];
#pragma unroll
            for (int j = 0; j < 4; ++j)
                o[j] = siluf(fmaf(rx[j][i + 3], w[j][3], fmaf(rx[j][i + 2], w[j][2],
                             fmaf(rx[j][i + 1], w[j][1], fmaf(rx[j][i], w[j][0], bb[j])))));
            *(float4*)&Xs[t4 + i][sg * 4] = make_float4(o[0], o[1], o[2], o[3]);
        }
    }
    {
        const int ch = sg * 4;
        float w[4][4], bb[4];
#pragma unroll
        for (int j = 0; j < 4; ++j) {
            bb[j] = b_conv[DINNER + ch + j];
#pragma unroll
            for (int k = 0; k < 4; ++k) w[j][k] = W_conv[(DINNER + ch + j) * 4 + k];
        }
        float rx[4][7];
#pragma unroll
        for (int r = 0; r < 7; ++r) {
            const int tg = tb + t4 - 3 + r;
            float4 v = make_float4(0.f, 0.f, 0.f, 0.f);
            if (tg >= 0) v = *(const float4*)(bcbuf + (row0 + tg) * BCW2 + ch);
            rx[0][r] = v.x; rx[1][r] = v.y; rx[2][r] = v.z; rx[3][r] = v.w;
        }
#pragma unroll
        for (int i = 0; i < 4; ++i) {
            const float wi = w_l[t4 + i];
            float o[4];
#pragma unroll
            for (int j = 0; j < 4; ++j)
                o[j] = wi * siluf(fmaf(rx[j][i + 3], w[j][3], fmaf(rx[j][i + 2], w[j][2],
                              fmaf(rx[j][i + 1], w[j][1], fmaf(rx[j][i], w[j][0], bb[j])))));
            *(float4*)&Bw[t4 + i][sg * 4] = make_float4(o[0], o[1], o[2], o[3]);
        }
    }
    __syncthreads();

    const int pn = tid & 15, pp = tid >> 4;
    const int n4 = pn * 4, p4 = pp * 4;
    float acc[4][4];
#pragma unroll
    for (int a = 0; a < 4; ++a)
#pragma unroll
        for (int d = 0; d < 4; ++d) acc[a][d] = 0.f;
#pragma unroll 4
    for (int i = 0; i < CHUNK; ++i) {
        const float4 xv = *(const float4*)&Xs[i][p4];
        const float4 bv = *(const float4*)&Bw[i][n4];
        const float xa[4] = {xv.x, xv.y, xv.z, xv.w};
        const float ba[4] = {bv.x, bv.y, bv.z, bv.w};
#pragma unroll
        for (int a = 0; a < 4; ++a)
#pragma unroll
            for (int d = 0; d < 4; ++d) acc[a][d] = fmaf(xa[a], ba[d], acc[a][d]);
    }
    const size_t so = (size_t)(bh * NCHUNK + c) * 4096;
#pragma unroll
    for (int a = 0; a < 4; ++a)
        *(float4*)(states + so + (size_t)(p4 + a) * 64 + n4) =
            make_float4(acc[a][0], acc[a][1], acc[a][2], acc[a][3]);
}

// ---------------------------------------------------------------------------
__global__ void chunk_scan(float* __restrict__ states, const float* __restrict__ dAprod)
{
    __shared__ float sdA[NCHUNK];
    const int bh = blockIdx.x >> 4;
    const int elem = ((blockIdx.x & 15) << 8) | threadIdx.x;
    if (threadIdx.x < NCHUNK) sdA[threadIdx.x] = dAprod[bh * NCHUNK + threadIdx.x];
    __syncthreads();
    const size_t base = (size_t)bh * NCHUNK * 4096 + elem;
    float s0 = 0.f;
    for (int c = 0; c < NCHUNK; ++c) {
        const size_t off = base + (size_t)c * 4096;
        const float Sc = states[off];
        states[off] = s0;
        s0 = fmaf(sdA[c], s0, Sc);
    }
}

// ---------------------------------------------------------------------------
// Phase B: outputs via 3 fp32 micro-GEMMs per (bh, chunk).
// 2-slot LDS (36 KB): Slot P = BcT -> ST -> Xs ; Slot Q = CcT -> MT (r18).
// ---------------------------------------------------------------------------
__launch_bounds__(256)
__global__ void scan_out(const float* __restrict__ xbuf, const float* __restrict__ bcbuf,
                         float* zbuf,
                         const float* __restrict__ dtT, const float* __restrict__ laT,
                         const float* __restrict__ W_conv, const float* __restrict__ b_conv,
                         const float* __restrict__ Dparam,
                         const float* __restrict__ states)
{
    __shared__ float BcT[CHUNK][LP];   // P: Bc[n][i] -> ST[n][p] -> Xs[t][p]
    __shared__ float CcT[CHUNK][LP];   // Q: Cc[n][t] -> MT[i][t]
    __shared__ float la_l[CHUNK], dt_l[CHUNK], a_l[CHUNK];
    float (*ST)[LP] = BcT;
    float (*MT)[LP] = CcT;
    float (*Xs)[LP] = BcT;             // staged after GEMM3 (ST dead)

    const int c = blockIdx.x, bh = blockIdx.y;
    const int b = bh >> 2, h = bh & 3;
    const int tid = threadIdx.x;
    const size_t row0 = (size_t)b * TSEQ;
    const int tb = c * CHUNK;
    const float Dh = Dparam[h];

    const int pS = tid >> 2;
    const int n16 = (tid & 3) * 16;
    const float* Sg = states + (size_t)(bh * NCHUNK + c) * 4096 + (size_t)pS * 64 + n16;
    const float4 sv0 = *(const float4*)(Sg + 0);
    const float4 sv1 = *(const float4*)(Sg + 4);
    const float4 sv2 = *(const float4*)(Sg + 8);
    const float4 sv3 = *(const float4*)(Sg + 12);

    if (tid < CHUNK) {
        const size_t o = (size_t)bh * TSEQ + tb + tid;
        const float la = laT[o];
        la_l[tid] = la;
        dt_l[tid] = dtT[o];
        a_l[tid] = __expf(la);
    }

    const int sg = tid & 15, st = tid >> 4;
    const int t4s = st * 4;

    {   // B -> BcT[n][i] (transposed store)
        const int ch = sg * 4;
        float w[4][4], bb[4];
#pragma unroll
        for (int j = 0; j < 4; ++j) {
            bb[j] = b_conv[DINNER + ch + j];
#pragma unroll
            for (int k = 0; k < 4; ++k) w[j][k] = W_conv[(DINNER + ch + j) * 4 + k];
        }
        float rx[4][7];
#pragma unroll
        for (int r = 0; r < 7; ++r) {
            const int tg = tb + t4s - 3 + r;
            float4 v = make_float4(0.f, 0.f, 0.f, 0.f);
            if (tg >= 0) v = *(const float4*)(bcbuf + (row0 + tg) * BCW2 + ch);
            rx[0][r] = v.x; rx[1][r] = v.y; rx[2][r] = v.z; rx[3][r] = v.w;
        }
#pragma unroll
        for (int j = 0; j < 4; ++j) {
            float o[4];
#pragma unroll
            for (int i = 0; i < 4; ++i)
                o[i] = siluf(fmaf(rx[j][i + 3], w[j][3], fmaf(rx[j][i + 2], w[j][2],
                             fmaf(rx[j][i + 1], w[j][1], fmaf(rx[j][i], w[j][0], bb[j])))));
            *(float4*)&BcT[ch + j][t4s] = make_float4(o[0], o[1], o[2], o[3]);
        }
    }
    {   // C -> CcT[n][t] (transposed store)
        const int ch = sg * 4;
        float w[4][4], bb[4];
#pragma unroll
        for (int j = 0; j < 4; ++j) {
            bb[j] = b_conv[DINNER + 64 + ch + j];
#pragma unroll
            for (int k = 0; k < 4; ++k) w[j][k] = W_conv[(DINNER + 64 + ch + j) * 4 + k];
        }
        float rx[4][7];
#pragma unroll
        for (int r = 0; r < 7; ++r) {
            const int tg = tb + t4s - 3 + r;
            float4 v = make_float4(0.f, 0.f, 0.f, 0.f);
            if (tg >= 0) v = *(const float4*)(bcbuf + (row0 + tg) * BCW2 + 64 + ch);
            rx[0][r] = v.x; rx[1][r] = v.y; rx[2][r] = v.z; rx[3][r] = v.w;
        }
#pragma unroll
        for (int j = 0; j < 4; ++j) {
            float o[4];
#pragma unroll
            for (int i = 0; i < 4; ++i)
                o[i] = siluf(fmaf(rx[j][i + 3], w[j][3], fmaf(rx[j][i + 2], w[j][2],
                             fmaf(rx[j][i + 1], w[j][1], fmaf(rx[j][i], w[j][0], bb[j])))));
            *(float4*)&CcT[ch + j][t4s] = make_float4(o[0], o[1], o[2], o[3]);
        }
    }
    __syncthreads();

    const int ti = tid & 15, tt = tid >> 4;
    const int i4 = ti * 4, t4 = tt * 4;

    // ---- GEMM1: M0[t][i] = C.B^T ----
    float m[4][4];
#pragma unroll
    for (int a = 0; a < 4; ++a)
#pragma unroll
        for (int d = 0; d < 4; ++d) m[a][d] = 0.f;
#pragma unroll 4
    for (int n = 0; n < 64; ++n) {
        const float4 cv = *(const float4*)&CcT[n][t4];
        const float4 bv = *(const float4*)&BcT[n][i4];
        const float ca[4] = {cv.x, cv.y, cv.z, cv.w};
        const float ba[4] = {bv.x, bv.y, bv.z, bv.w};
#pragma unroll
        for (int a = 0; a < 4; ++a)
#pragma unroll
            for (int d = 0; d < 4; ++d) m[a][d] = fmaf(ca[a], ba[d], m[a][d]);
    }
    // decay + causal mask (mask BEFORE exp)
    {
        float lat[4], lai[4], dti[4];
#pragma unroll
        for (int a = 0; a < 4; ++a) lat[a] = la_l[t4 + a];
#pragma unroll
        for (int d = 0; d < 4; ++d) { lai[d] = la_l[i4 + d]; dti[d] = dt_l[i4 + d]; }
#pragma unroll
        for (int a = 0; a < 4; ++a)
#pragma unroll
            for (int d = 0; d < 4; ++d) {
                if (i4 + d <= t4 + a)
                    m[a][d] = m[a][d] * dti[d] * __expf(lat[a] - lai[d]);
                else
                    m[a][d] = 0.f;
            }
    }
    __syncthreads();   // all waves done reading BcT

    // ---- ST[n][p] = S_old[p][n] (slot P) ----
    {
        const float sa[16] = {sv0.x, sv0.y, sv0.z, sv0.w, sv1.x, sv1.y, sv1.z, sv1.w,
                              sv2.x, sv2.y, sv2.z, sv2.w, sv3.x, sv3.y, sv3.z, sv3.w};
#pragma unroll
        for (int q = 0; q < 16; ++q) ST[n16 + q][pS] = sa[q];
    }
    __syncthreads();

    // ---- GEMM3: Y2[t][p] = C.S^T ----
    float y2[4][4];
#pragma unroll
    for (int a = 0; a < 4; ++a)
#pragma unroll
        for (int d = 0; d < 4; ++d) y2[a][d] = 0.f;
#pragma unroll 4
    for (int n = 0; n < 64; ++n) {
        const float4 cv = *(const float4*)&CcT[n][t4];
        const float4 sv = *(const float4*)&ST[n][i4];
        const float ca[4] = {cv.x, cv.y, cv.z, cv.w};
        const float sa[4] = {sv.x, sv.y, sv.z, sv.w};
#pragma unroll
        for (int a = 0; a < 4; ++a)
#pragma unroll
            for (int d = 0; d < 4; ++d) y2[a][d] = fmaf(ca[a], sa[d], y2[a][d]);
    }
    __syncthreads();   // GEMM3 done: ST (slot P) and Cc (slot Q) both dead

    // ---- MT[i][t] = M[t][i] (slot Q)  +  Xs[t][p] staging (slot P) ----
#pragma unroll
    for (int d = 0; d < 4; ++d)
        *(float4*)&MT[i4 + d][t4] = make_float4(m[0][d], m[1][d], m[2][d], m[3][d]);
    {   // X -> Xs[t][p]: conv+silu of x, this head's 64 channels
        const int ch = h * HEADDIM + sg * 4;
        float w[4][4], bb[4];
#pragma unroll
        for (int j = 0; j < 4; ++j) {
            bb[j] = b_conv[ch + j];
#pragma unroll
            for (int k = 0; k < 4; ++k) w[j][k] = W_conv[(ch + j) * 4 + k];
        }
        float rx[4][7];
#pragma unroll
        for (int r = 0; r < 7; ++r) {
            const int tg = tb + t4s - 3 + r;
            float4 v = make_float4(0.f, 0.f, 0.f, 0.f);
            if (tg >= 0) v = *(const float4*)(xbuf + (row0 + tg) * DINNER + ch);
            rx[0][r] = v.x; rx[1][r] = v.y; rx[2][r] = v.z; rx[3][r] = v.w;
        }
#pragma unroll
        for (int i = 0; i < 4; ++i) {
            float o[4];
#pragma unroll
            for (int j = 0; j < 4; ++j)
                o[j] = siluf(fmaf(rx[j][i + 3], w[j][3], fmaf(rx[j][i + 2], w[j][2],
                             fmaf(rx[j][i + 1], w[j][1], fmaf(rx[j][i], w[j][0], bb[j])))));
            *(float4*)&Xs[t4s + i][sg * 4] = make_float4(o[0], o[1], o[2], o[3]);
        }
    }
    __syncthreads();

    // ---- GEMM2: Yac[t][p] = M.X ----
    float yac[4][4];
#pragma unroll
    for (int a = 0; a < 4; ++a)
#pragma unroll
        for (int d = 0; d < 4; ++d) yac[a][d] = 0.f;
#pragma unroll 4
    for (int k = 0; k < CHUNK; ++k) {
        const float4 mv = *(const float4*)&MT[k][t4];
        const float4 xv = *(const float4*)&Xs[k][i4];
        const float ma[4] = {mv.x, mv.y, mv.z, mv.w};
        const float xa[4] = {xv.x, xv.y, xv.z, xv.w};
#pragma unroll
        for (int a = 0; a < 4; ++a)
#pragma unroll
            for (int d = 0; d < 4; ++d) yac[a][d] = fmaf(ma[a], xa[d], yac[a][d]);
    }

    // ---- epilogue: Y = Yac + a[t]*Y2 + D*X ; g = Y*silu(z) -> zbuf ----
#pragma unroll
    for (int a = 0; a < 4; ++a) {
        const int t = t4 + a;
        const float at = a_l[t];
        const float4 xv = *(const float4*)&Xs[t][i4];
        const float xa[4] = {xv.x, xv.y, xv.z, xv.w};
        float* zp = zbuf + (row0 + tb + t) * DINNER + h * HEADDIM + i4;
        const float4 zv = *(const float4*)zp;
        const float za[4] = {zv.x, zv.y, zv.z, zv.w};
        float g[4];
#pragma unroll
        for (int d = 0; d < 4; ++d) {
            const float Y = yac[a][d] + at * y2[a][d] + Dh * xa[d];
            g[d] = Y * siluf(za[d]);
        }
        *(float4*)zp = make_float4(g[0], g[1], g[2], g[3]);
    }
}

// ---------------------------------------------------------------------------
__launch_bounds__(256)
__global__ void rms_val(const float* __restrict__ g, const float* __restrict__ Wv,
                        const float* __restrict__ bval, float* __restrict__ values,
                        unsigned short* __restrict__ Ghi, unsigned short* __restrict__ Glo)
{
    const size_t tok = (size_t)blockIdx.x * 4 + (threadIdx.x >> 6);
    const int lane = threadIdx.x & 63;
    const float4 v = *(const float4*)(g + tok * DINNER + lane * 4);
    const float4 w = *(const float4*)(Wv + lane * 4);
    float ssq = v.x * v.x + v.y * v.y + v.z * v.z + v.w * v.w;
    float gw  = v.x * w.x + v.y * w.y + v.z * w.z + v.w * w.w;
#pragma unroll
    for (int d = 1; d < 64; d <<= 1) {
        ssq += __shfl_xor(ssq, d, 64);
        gw  += __shfl_xor(gw, d, 64);
    }
    const float rms = rsqrtf(ssq * (1.f / DINNER) + 1e-5f);
    u16x4 h, l;
    splitbf(v.x * rms, ((unsigned short*)&h)[0], ((unsigned short*)&l)[0]);
    splitbf(v.y * rms, ((unsigned short*)&h)[1], ((unsigned short*)&l)[1]);
    splitbf(v.z * rms, ((unsigned short*)&h)[2], ((unsigned short*)&l)[2]);
    splitbf(v.w * rms, ((unsigned short*)&h)[3], ((unsigned short*)&l)[3]);
    *(u16x4*)(Ghi + tok * DINNER + lane * 4) = h;
    *(u16x4*)(Glo + tok * DINNER + lane * 4) = l;
    if (lane == 0) values[tok] = gw * rms + bval[0];
}

// ---------------------------------------------------------------------------
extern "C" void kernel_launch(void* const* d_in, const int* in_sizes, int n_in,
                              void* d_out, int out_size, void* d_ws, size_t ws_size,
                              hipStream_t stream)
{
    (void)in_sizes; (void)n_in; (void)out_size; (void)ws_size;
    const float* obs     = (const float*)d_in[0];
    const float* W_enc   = (const float*)d_in[1];
    const float* b_enc   = (const float*)d_in[2];
    const float* W_in    = (const float*)d_in[3];
    const float* W_conv  = (const float*)d_in[4];
    const float* b_conv  = (const float*)d_in[5];
    const float* dt_bias = (const float*)d_in[6];
    const float* A_log   = (const float*)d_in[7];
    const float* Dp      = (const float*)d_in[8];
    const float* norm_w  = (const float*)d_in[9];
    const float* W_out   = (const float*)d_in[10];
    const float* W_act   = (const float*)d_in[11];
    const float* b_act   = (const float*)d_in[12];
    const float* W_val   = (const float*)d_in[13];
    const float* b_val   = (const float*)d_in[14];

    float* logits = (float*)d_out;
    float* values = logits + (size_t)NTOK * NACT;

    char* ws = (char*)d_ws;
    size_t off = 0;
    auto alloc = [&](size_t nbytes) {
        char* ptr = ws + off;
        off += (nbytes + 255) / 256 * 256;
        return ptr;
    };
    float* zbuf   = (float*)alloc((size_t)NTOK * DINNER * 4);   // z -> g in place
    float* xbuf   = (float*)alloc((size_t)NTOK * DINNER * 4);
    float* bcbuf  = (float*)alloc((size_t)NTOK * BCW2 * 4);
    float* dtcol  = (float*)alloc((size_t)NTOK * 4 * 4);
    // shared 134.2 MB region: states (scan) -> g-bf16 (rms_val/logits)
    char*  shared = alloc((size_t)NTOK * OBSD * 2 * 2);
    float* states = (float*)shared;
    unsigned short* Ghi = (unsigned short*)shared;
    unsigned short* Glo = Ghi + (size_t)NTOK * DINNER;
    float* dtT    = (float*)alloc((size_t)NBATCH * NHEADS * TSEQ * 4);
    float* laT    = (float*)alloc((size_t)NBATCH * NHEADS * TSEQ * 4);
    float* dApb   = (float*)alloc(NBATCH * NHEADS * NCHUNK * 4);
    unsigned short* WcThi = (unsigned short*)alloc((size_t)NPPAD * OBSD * 2);
    unsigned short* WcTlo = (unsigned short*)alloc((size_t)NPPAD * OBSD * 2);
    float* bz     = (float*)alloc(NPPAD * 4);
    unsigned short* WhThi = (unsigned short*)alloc((size_t)NACT * DINNER * 2);
    unsigned short* WhTlo = (unsigned short*)alloc((size_t)NACT * DINNER * 2);
    float* Wv     = (float*)alloc(DINNER * 4);

    fuse_whead<<<DINNER, NACT, 0, stream>>>(W_out, W_act, W_val, norm_w, WhThi, WhTlo, Wv);
    make_wc<<<NPPAD, 256, 0, stream>>>(W_enc, W_in, b_enc, WcThi, WcTlo, bz);
    // in_proj: A staged from fp32 obs, split in-register (conv_obs deleted)
    mfma_gemm<1><<<dim3(NPPAD / 64, NTOK / 128), 256, 0, stream>>>(
        obs, nullptr, nullptr, WcThi, WcTlo, OBSD, bz, nullptr, zbuf, xbuf, bcbuf, dtcol);
    prep_scan<<<NBATCH * NHEADS * NCHUNK, 64, 0, stream>>>(
        dtcol, dt_bias, A_log, dtT, laT, dApb);
    scan_state<<<dim3(NCHUNK, NBATCH * NHEADS), 256, 0, stream>>>(
        xbuf, bcbuf, dtT, laT, W_conv, b_conv, states);
    chunk_scan<<<NBATCH * NHEADS * 16, 256, 0, stream>>>(states, dApb);
    scan_out<<<dim3(NCHUNK, NBATCH * NHEADS), 256, 0, stream>>>(
        xbuf, bcbuf, zbuf, dtT, laT, W_conv, b_conv, Dp, states);
    rms_val<<<NTOK / 4, 256, 0, stream>>>(zbuf, Wv, b_val, values, Ghi, Glo);
    mfma_gemm<0><<<dim3(1, NTOK / 128), 256, 0, stream>>>(
        nullptr, Ghi, Glo, WhThi, WhTlo, DINNER, b_act, logits, nullptr, nullptr, nullptr, nullptr);
}

// Round 22
// 780.008 us; speedup vs baseline: 1.0631x; 1.0281x over previous
//
#include <hip/hip_runtime.h>
#include <math.h>

#define OBSD   256
#define TSEQ   4096
#define NBATCH 32
#define DMODEL 128
#define DSTATE 64
#define DINNER 256
#define NHEADS 4
#define HEADDIM 64
#define NPROJ  644
#define NPPAD  704   // in_proj N padded to 11*64
#define NTOK   (NBATCH*TSEQ)
#define CHUNK  64
#define NCHUNK (TSEQ/CHUNK)
#define NACT   64
#define BCW2   128   // bcbuf row width (B 64 | C 64)
#define LP     68    // padded LDS row stride (scan kernels)

typedef __attribute__((ext_vector_type(8))) short bf16x8;
typedef __attribute__((ext_vector_type(4))) float f32x4;
typedef __attribute__((ext_vector_type(8))) unsigned short u16x8;
typedef __attribute__((ext_vector_type(4))) unsigned short u16x4;

__device__ __forceinline__ float siluf(float x) { return x / (1.f + __expf(-x)); }

// round-to-nearest-even bf16 (bit pattern) and hi/lo split: v ~= hi + lo
__device__ __forceinline__ unsigned short bfhi(float v) {
    unsigned u = __float_as_uint(v);
    return (unsigned short)((u + 0x7FFFu + ((u >> 16) & 1u)) >> 16);
}
__device__ __forceinline__ void splitbf(float v, unsigned short& hi, unsigned short& lo) {
    hi = bfhi(v);
    const float hf = __uint_as_float((unsigned)hi << 16);
    lo = bfhi(v - hf);
}

// ---------------------------------------------------------------------------
// Split-bf16 MFMA GEMM (HW-verified round 10).
// SEG=1 stages A directly from fp32 (obs), splitting to bf16 hi/lo
// in-register (r19). r22: XCD-aware block swizzle (bijective, nwg%8==0):
// each XCD owns a contiguous row-block span so the 11 column-tiles sharing
// an A-tile hit the SAME L2 (cuts A re-fetch). Pure index remap ->
// bit-identical output. SEG=0 keeps bf16 A path, no swizzle.
// ---------------------------------------------------------------------------
template<int SEG>
__launch_bounds__(256)
__global__ void mfma_gemm(const float* __restrict__ Af32,
                          const unsigned short* __restrict__ Ahi,
                          const unsigned short* __restrict__ Alo,
                          const unsigned short* __restrict__ BThi,
                          const unsigned short* __restrict__ BTlo,
                          int K, const float* __restrict__ bias,
                          float* __restrict__ C,
                          float* __restrict__ zbuf, float* __restrict__ xbuf,
                          float* __restrict__ bcbuf, float* __restrict__ dtcol)
{
    __shared__ __align__(16) unsigned short Ah[128][40], Al[128][40];
    __shared__ __align__(16) unsigned short Bh[64][40],  Bl[64][40];
    const int tid  = threadIdx.x;
    const int wave = tid >> 6, lane = tid & 63;
    const int l15 = lane & 15, l4 = lane >> 4;

    int m0, n0;
    if constexpr (SEG == 1) {
        // XCD swizzle: lin dispatch order round-robins XCDs; remap so each
        // XCD gets a contiguous swz range (nwg = 11*1024 = 11264, /8 = 1408).
        const int nbx = gridDim.x;                       // 11
        const int nwg = nbx * gridDim.y;                 // 11264
        const int lin = blockIdx.y * nbx + blockIdx.x;
        const int swz = (lin & 7) * (nwg >> 3) + (lin >> 3);
        m0 = (swz / nbx) * 128;
        n0 = (swz % nbx) * 64;
    } else {
        m0 = blockIdx.y * 128;
        n0 = blockIdx.x * 64;
    }

    f32x4 acc[2][4];
#pragma unroll
    for (int rt = 0; rt < 2; ++rt)
#pragma unroll
        for (int ct = 0; ct < 4; ++ct) acc[rt][ct] = (f32x4){0.f, 0.f, 0.f, 0.f};

    const int ar  = tid >> 1;           // A row 0..127
    const int akc = (tid & 1) * 16;     // k chunk base
    const int br  = tid >> 2;           // B row (n)
    const int bkc = (tid & 3) * 8;

    for (int k0 = 0; k0 < K; k0 += 32) {
        if constexpr (SEG == 1) {
            // stage A from fp32, split in-register (replaces conv_obs)
            const float* ap = Af32 + (size_t)(m0 + ar) * K + k0 + akc;
#pragma unroll
            for (int half = 0; half < 2; ++half) {
                const float4 v0 = *(const float4*)(ap + half * 8);
                const float4 v1 = *(const float4*)(ap + half * 8 + 4);
                const float va[8] = {v0.x, v0.y, v0.z, v0.w, v1.x, v1.y, v1.z, v1.w};
                u16x8 hh, ll;
#pragma unroll
                for (int e = 0; e < 8; ++e)
                    splitbf(va[e], ((unsigned short*)&hh)[e], ((unsigned short*)&ll)[e]);
                *(u16x8*)&Ah[ar][akc + half * 8] = hh;
                *(u16x8*)&Al[ar][akc + half * 8] = ll;
            }
        } else {
            const size_t ab = (size_t)(m0 + ar) * K + k0 + akc;
            *(u16x8*)&Ah[ar][akc]     = *(const u16x8*)(Ahi + ab);
            *(u16x8*)&Ah[ar][akc + 8] = *(const u16x8*)(Ahi + ab + 8);
            *(u16x8*)&Al[ar][akc]     = *(const u16x8*)(Alo + ab);
            *(u16x8*)&Al[ar][akc + 8] = *(const u16x8*)(Alo + ab + 8);
        }
        {
            const size_t bb = (size_t)(n0 + br) * K + k0 + bkc;
            *(u16x8*)&Bh[br][bkc] = *(const u16x8*)(BThi + bb);
            *(u16x8*)&Bl[br][bkc] = *(const u16x8*)(BTlo + bb);
        }
        __syncthreads();

        const int kk = l4 * 8;
        bf16x8 ah[2], al[2], bh[4], bl[4];
#pragma unroll
        for (int rt = 0; rt < 2; ++rt) {
            const int r = wave * 32 + rt * 16 + l15;
            ah[rt] = *(const bf16x8*)&Ah[r][kk];
            al[rt] = *(const bf16x8*)&Al[r][kk];
        }
#pragma unroll
        for (int ct = 0; ct < 4; ++ct) {
            const int n = ct * 16 + l15;
            bh[ct] = *(const bf16x8*)&Bh[n][kk];
            bl[ct] = *(const bf16x8*)&Bl[n][kk];
        }
#pragma unroll
        for (int rt = 0; rt < 2; ++rt)
#pragma unroll
            for (int ct = 0; ct < 4; ++ct) {
                acc[rt][ct] = __builtin_amdgcn_mfma_f32_16x16x32_bf16(ah[rt], bh[ct], acc[rt][ct], 0, 0, 0);
                acc[rt][ct] = __builtin_amdgcn_mfma_f32_16x16x32_bf16(ah[rt], bl[ct], acc[rt][ct], 0, 0, 0);
                acc[rt][ct] = __builtin_amdgcn_mfma_f32_16x16x32_bf16(al[rt], bh[ct], acc[rt][ct], 0, 0, 0);
            }
        __syncthreads();
    }

#pragma unroll
    for (int rt = 0; rt < 2; ++rt) {
        const int rbase = m0 + wave * 32 + rt * 16 + l4 * 4;
#pragma unroll
        for (int ct = 0; ct < 4; ++ct) {
            const int cg = n0 + ct * 16 + l15;
            const float bv = bias[cg];
#pragma unroll
            for (int j = 0; j < 4; ++j) {
                const float v = acc[rt][ct][j] + bv;
                const size_t r = (size_t)(rbase + j);
                if constexpr (SEG == 0) {
                    C[r * NACT + cg] = v;
                } else {
                    if (cg < 256)      zbuf[r * DINNER + cg] = v;
                    else if (cg < 512) xbuf[r * DINNER + (cg - 256)] = v;
                    else if (cg < 640) bcbuf[r * BCW2 + (cg - 512)] = v;
                    else if (cg < NPROJ) dtcol[r * 4 + (cg - 640)] = v;
                }
            }
        }
    }
}

// ---------------------------------------------------------------------------
__global__ void make_wc(const float* __restrict__ W_enc, const float* __restrict__ W_in,
                        const float* __restrict__ b_enc,
                        unsigned short* __restrict__ WcThi, unsigned short* __restrict__ WcTlo,
                        float* __restrict__ bz)
{
    const int n = blockIdx.x;
    const int r = threadIdx.x;
    float v = 0.f;
    if (n < NPROJ)
        for (int k = 0; k < DMODEL; ++k)
            v = fmaf(W_enc[r * DMODEL + k], W_in[k * NPROJ + n], v);
    unsigned short hi, lo; splitbf(v, hi, lo);
    WcThi[n * OBSD + r] = hi;
    WcTlo[n * OBSD + r] = lo;
    if (r == 0) {
        float bv = 0.f;
        if (n < NPROJ)
            for (int k = 0; k < DMODEL; ++k)
                bv = fmaf(b_enc[k], W_in[k * NPROJ + n], bv);
        bz[n] = bv;
    }
}

// ---------------------------------------------------------------------------
__global__ void fuse_whead(const float* __restrict__ W_out, const float* __restrict__ W_act,
                           const float* __restrict__ W_val, const float* __restrict__ norm_w,
                           unsigned short* __restrict__ WhThi, unsigned short* __restrict__ WhTlo,
                           float* __restrict__ Wv)
{
    const int k = blockIdx.x;
    const int j = threadIdx.x;
    float s = 0.f;
    for (int m = 0; m < DMODEL; ++m)
        s = fmaf(W_out[k * DMODEL + m], W_act[m * NACT + j], s);
    s *= norm_w[k];
    unsigned short hi, lo; splitbf(s, hi, lo);
    WhThi[j * DINNER + k] = hi;
    WhTlo[j * DINNER + k] = lo;
    if (j == 0) {
        float sv = 0.f;
        for (int m = 0; m < DMODEL; ++m)
            sv = fmaf(W_out[k * DMODEL + m], W_val[m], sv);
        Wv[k] = sv * norm_w[k];
    }
}

// ---------------------------------------------------------------------------
__global__ void prep_scan(const float* __restrict__ dtcol, const float* __restrict__ dt_bias,
                          const float* __restrict__ A_log,
                          float* __restrict__ dtT, float* __restrict__ laT,
                          float* __restrict__ dApbuf)
{
    const int bc = blockIdx.x;
    const int bh = bc >> 6, c = bc & 63;
    const int b = bh >> 2, h = bh & 3;
    const int lane = threadIdx.x;
    const size_t tok = (size_t)b * TSEQ + c * CHUNK + lane;
    const float x = dtcol[tok * 4 + h] + dt_bias[h];
    const float dt = (x > 20.f) ? x : log1pf(expf(x));
    const float A = -expf(A_log[h]);
    float v = dt * A;
#pragma unroll
    for (int d = 1; d < 64; d <<= 1) {
        const float o = __shfl_up(v, d, 64);
        if (lane >= d) v += o;
    }
    const size_t o = (size_t)bh * TSEQ + c * CHUNK + lane;
    dtT[o] = dt;
    laT[o] = v;
    if (lane == 63) dApbuf[bh * NCHUNK + c] = __expf(v);
}

// ---------------------------------------------------------------------------
// Phase A: chunk-local states via GEMM (fp32 VALU — passed r9..r21).
// ---------------------------------------------------------------------------
__launch_bounds__(256)
__global__ void scan_state(const float* __restrict__ xbuf, const float* __restrict__ bcbuf,
                           const float* __restrict__ dtT, const float* __restrict__ laT,
                           const float* __restrict__ W_conv, const float* __restrict__ b_conv,
                           float* __restrict__ states)
{
    __shared__ float Xs[CHUNK][LP];
    __shared__ float Bw[CHUNK][LP];
    __shared__ float w_l[CHUNK];
    const int c = blockIdx.x, bh = blockIdx.y;
    const int b = bh >> 2, h = bh & 3;
    const int tid = threadIdx.x;
    const size_t row0 = (size_t)b * TSEQ;
    const int tb = c * CHUNK;

    if (tid < CHUNK) {
        const size_t o = (size_t)bh * TSEQ + tb;
        const float laLast = laT[o + CHUNK - 1];
        w_l[tid] = dtT[o + tid] * __expf(laLast - laT[o + tid]);
    }
    __syncthreads();

    const int sg = tid & 15, st = tid >> 4;
    const int t4 = st * 4;

    {
        const int ch = h * HEADDIM + sg * 4;
        float w[4][4], bb[4];
#pragma unroll
        for (int j = 0; j < 4; ++j) {
            bb[j] = b_conv[ch + j];
#pragma unroll
            for (int k = 0; k < 4; ++k) w[j][k] = W_conv[(ch + j) * 4 + k];
        }
        float rx[4][7];
#pragma unroll
        for (int r = 0; r < 7; ++r) {
            const int tg = tb + t4 - 3 + r;
            float4 v = make_float4(0.f, 0.f, 0.f, 0.f);
            if (tg >= 0) v = *(const float4*)(xbuf + (row0 + tg) * DINNER + ch);
            rx[0][r] = v.x; rx[1][r] = v.y; rx[2][r] = v.z; rx[3][r] = v.w;
        }
#pragma unroll
        for (int i = 0; i < 4; ++i) {
            float o[4];
#pragma unroll
            for (int j = 0; j < 4; ++j)
                o[j] = siluf(fmaf(rx[j][i + 3], w[j][3], fmaf(rx[j][i + 2], w[j][2],
                             fmaf(rx[j][i + 1], w[j][1], fmaf(rx[j][i], w[j][0], bb[j])))));
            *(float4*)&Xs[t4 + i][sg * 4] = make_float4(o[0], o[1], o[2], o[3]);
        }
    }
    {
        const int ch = sg * 4;
        float w[4][4], bb[4];
#pragma unroll
        for (int j = 0; j < 4; ++j) {
            bb[j] = b_conv[DINNER + ch + j];
#pragma unroll
            for (int k = 0; k < 4; ++k) w[j][k] = W_conv[(DINNER + ch + j) * 4 + k];
        }
        float rx[4][7];
#pragma unroll
        for (int r = 0; r < 7; ++r) {
            const int tg = tb + t4 - 3 + r;
            float4 v = make_float4(0.f, 0.f, 0.f, 0.f);
            if (tg >= 0) v = *(const float4*)(bcbuf + (row0 + tg) * BCW2 + ch);
            rx[0][r] = v.x; rx[1][r] = v.y; rx[2][r] = v.z; rx[3][r] = v.w;
        }
#pragma unroll
        for (int i = 0; i < 4; ++i) {
            const float wi = w_l[t4 + i];
            float o[4];
#pragma unroll
            for (int j = 0; j < 4; ++j)
                o[j] = wi * siluf(fmaf(rx[j][i + 3], w[j][3], fmaf(rx[j][i + 2], w[j][2],
                              fmaf(rx[j][i + 1], w[j][1], fmaf(rx[j][i], w[j][0], bb[j])))));
            *(float4*)&Bw[t4 + i][sg * 4] = make_float4(o[0], o[1], o[2], o[3]);
        }
    }
    __syncthreads();

    const int pn = tid & 15, pp = tid >> 4;
    const int n4 = pn * 4, p4 = pp * 4;
    float acc[4][4];
#pragma unroll
    for (int a = 0; a < 4; ++a)
#pragma unroll
        for (int d = 0; d < 4; ++d) acc[a][d] = 0.f;
#pragma unroll 4
    for (int i = 0; i < CHUNK; ++i) {
        const float4 xv = *(const float4*)&Xs[i][p4];
        const float4 bv = *(const float4*)&Bw[i][n4];
        const float xa[4] = {xv.x, xv.y, xv.z, xv.w};
        const float ba[4] = {bv.x, bv.y, bv.z, bv.w};
#pragma unroll
        for (int a = 0; a < 4; ++a)
#pragma unroll
            for (int d = 0; d < 4; ++d) acc[a][d] = fmaf(xa[a], ba[d], acc[a][d]);
    }
    const size_t so = (size_t)(bh * NCHUNK + c) * 4096;
#pragma unroll
    for (int a = 0; a < 4; ++a)
        *(float4*)(states + so + (size_t)(p4 + a) * 64 + n4) =
            make_float4(acc[a][0], acc[a][1], acc[a][2], acc[a][3]);
}

// ---------------------------------------------------------------------------
__global__ void chunk_scan(float* __restrict__ states, const float* __restrict__ dAprod)
{
    __shared__ float sdA[NCHUNK];
    const int bh = blockIdx.x >> 4;
    const int elem = ((blockIdx.x & 15) << 8) | threadIdx.x;
    if (threadIdx.x < NCHUNK) sdA[threadIdx.x] = dAprod[bh * NCHUNK + threadIdx.x];
    __syncthreads();
    const size_t base = (size_t)bh * NCHUNK * 4096 + elem;
    float s0 = 0.f;
    for (int c = 0; c < NCHUNK; ++c) {
        const size_t off = base + (size_t)c * 4096;
        const float Sc = states[off];
        states[off] = s0;
        s0 = fmaf(sdA[c], s0, Sc);
    }
}

// ---------------------------------------------------------------------------
// Phase B: outputs via 3 fp32 micro-GEMMs per (bh, chunk).
// 2-slot LDS (36 KB): Slot P = BcT -> ST -> Xs ; Slot Q = CcT -> MT (r18).
// ---------------------------------------------------------------------------
__launch_bounds__(256)
__global__ void scan_out(const float* __restrict__ xbuf, const float* __restrict__ bcbuf,
                         float* zbuf,
                         const float* __restrict__ dtT, const float* __restrict__ laT,
                         const float* __restrict__ W_conv, const float* __restrict__ b_conv,
                         const float* __restrict__ Dparam,
                         const float* __restrict__ states)
{
    __shared__ float BcT[CHUNK][LP];   // P: Bc[n][i] -> ST[n][p] -> Xs[t][p]
    __shared__ float CcT[CHUNK][LP];   // Q: Cc[n][t] -> MT[i][t]
    __shared__ float la_l[CHUNK], dt_l[CHUNK], a_l[CHUNK];
    float (*ST)[LP] = BcT;
    float (*MT)[LP] = CcT;
    float (*Xs)[LP] = BcT;             // staged after GEMM3 (ST dead)

    const int c = blockIdx.x, bh = blockIdx.y;
    const int b = bh >> 2, h = bh & 3;
    const int tid = threadIdx.x;
    const size_t row0 = (size_t)b * TSEQ;
    const int tb = c * CHUNK;
    const float Dh = Dparam[h];

    const int pS = tid >> 2;
    const int n16 = (tid & 3) * 16;
    const float* Sg = states + (size_t)(bh * NCHUNK + c) * 4096 + (size_t)pS * 64 + n16;
    const float4 sv0 = *(const float4*)(Sg + 0);
    const float4 sv1 = *(const float4*)(Sg + 4);
    const float4 sv2 = *(const float4*)(Sg + 8);
    const float4 sv3 = *(const float4*)(Sg + 12);

    if (tid < CHUNK) {
        const size_t o = (size_t)bh * TSEQ + tb + tid;
        const float la = laT[o];
        la_l[tid] = la;
        dt_l[tid] = dtT[o];
        a_l[tid] = __expf(la);
    }

    const int sg = tid & 15, st = tid >> 4;
    const int t4s = st * 4;

    {   // B -> BcT[n][i] (transposed store)
        const int ch = sg * 4;
        float w[4][4], bb[4];
#pragma unroll
        for (int j = 0; j < 4; ++j) {
            bb[j] = b_conv[DINNER + ch + j];
#pragma unroll
            for (int k = 0; k < 4; ++k) w[j][k] = W_conv[(DINNER + ch + j) * 4 + k];
        }
        float rx[4][7];
#pragma unroll
        for (int r = 0; r < 7; ++r) {
            const int tg = tb + t4s - 3 + r;
            float4 v = make_float4(0.f, 0.f, 0.f, 0.f);
            if (tg >= 0) v = *(const float4*)(bcbuf + (row0 + tg) * BCW2 + ch);
            rx[0][r] = v.x; rx[1][r] = v.y; rx[2][r] = v.z; rx[3][r] = v.w;
        }
#pragma unroll
        for (int j = 0; j < 4; ++j) {
            float o[4];
#pragma unroll
            for (int i = 0; i < 4; ++i)
                o[i] = siluf(fmaf(rx[j][i + 3], w[j][3], fmaf(rx[j][i + 2], w[j][2],
                             fmaf(rx[j][i + 1], w[j][1], fmaf(rx[j][i], w[j][0], bb[j])))));
            *(float4*)&BcT[ch + j][t4s] = make_float4(o[0], o[1], o[2], o[3]);
        }
    }
    {   // C -> CcT[n][t] (transposed store)
        const int ch = sg * 4;
        float w[4][4], bb[4];
#pragma unroll
        for (int j = 0; j < 4; ++j) {
            bb[j] = b_conv[DINNER + 64 + ch + j];
#pragma unroll
            for (int k = 0; k < 4; ++k) w[j][k] = W_conv[(DINNER + 64 + ch + j) * 4 + k];
        }
        float rx[4][7];
#pragma unroll
        for (int r = 0; r < 7; ++r) {
            const int tg = tb + t4s - 3 + r;
            float4 v = make_float4(0.f, 0.f, 0.f, 0.f);
            if (tg >= 0) v = *(const float4*)(bcbuf + (row0 + tg) * BCW2 + 64 + ch);
            rx[0][r] = v.x; rx[1][r] = v.y; rx[2][r] = v.z; rx[3][r] = v.w;
        }
#pragma unroll
        for (int j = 0; j < 4; ++j) {
            float o[4];
#pragma unroll
            for (int i = 0; i < 4; ++i)
                o[i] = siluf(fmaf(rx[j][i + 3], w[j][3], fmaf(rx[j][i + 2], w[j][2],
                             fmaf(rx[j][i + 1], w[j][1], fmaf(rx[j][i], w[j][0], bb[j])))));
            *(float4*)&CcT[ch + j][t4s] = make_float4(o[0], o[1], o[2], o[3]);
        }
    }
    __syncthreads();

    const int ti = tid & 15, tt = tid >> 4;
    const int i4 = ti * 4, t4 = tt * 4;

    // ---- GEMM1: M0[t][i] = C.B^T ----
    float m[4][4];
#pragma unroll
    for (int a = 0; a < 4; ++a)
#pragma unroll
        for (int d = 0; d < 4; ++d) m[a][d] = 0.f;
#pragma unroll 4
    for (int n = 0; n < 64; ++n) {
        const float4 cv = *(const float4*)&CcT[n][t4];
        const float4 bv = *(const float4*)&BcT[n][i4];
        const float ca[4] = {cv.x, cv.y, cv.z, cv.w};
        const float ba[4] = {bv.x, bv.y, bv.z, bv.w};
#pragma unroll
        for (int a = 0; a < 4; ++a)
#pragma unroll
            for (int d = 0; d < 4; ++d) m[a][d] = fmaf(ca[a], ba[d], m[a][d]);
    }
    // decay + causal mask (mask BEFORE exp)
    {
        float lat[4], lai[4], dti[4];
#pragma unroll
        for (int a = 0; a < 4; ++a) lat[a] = la_l[t4 + a];
#pragma unroll
        for (int d = 0; d < 4; ++d) { lai[d] = la_l[i4 + d]; dti[d] = dt_l[i4 + d]; }
#pragma unroll
        for (int a = 0; a < 4; ++a)
#pragma unroll
            for (int d = 0; d < 4; ++d) {
                if (i4 + d <= t4 + a)
                    m[a][d] = m[a][d] * dti[d] * __expf(lat[a] - lai[d]);
                else
                    m[a][d] = 0.f;
            }
    }
    __syncthreads();   // all waves done reading BcT

    // ---- ST[n][p] = S_old[p][n] (slot P) ----
    {
        const float sa[16] = {sv0.x, sv0.y, sv0.z, sv0.w, sv1.x, sv1.y, sv1.z, sv1.w,
                              sv2.x, sv2.y, sv2.z, sv2.w, sv3.x, sv3.y, sv3.z, sv3.w};
#pragma unroll
        for (int q = 0; q < 16; ++q) ST[n16 + q][pS] = sa[q];
    }
    __syncthreads();

    // ---- GEMM3: Y2[t][p] = C.S^T ----
    float y2[4][4];
#pragma unroll
    for (int a = 0; a < 4; ++a)
#pragma unroll
        for (int d = 0; d < 4; ++d) y2[a][d] = 0.f;
#pragma unroll 4
    for (int n = 0; n < 64; ++n) {
        const float4 cv = *(const float4*)&CcT[n][t4];
        const float4 sv = *(const float4*)&ST[n][i4];
        const float ca[4] = {cv.x, cv.y, cv.z, cv.w};
        const float sa[4] = {sv.x, sv.y, sv.z, sv.w};
#pragma unroll
        for (int a = 0; a < 4; ++a)
#pragma unroll
            for (int d = 0; d < 4; ++d) y2[a][d] = fmaf(ca[a], sa[d], y2[a][d]);
    }
    __syncthreads();   // GEMM3 done: ST (slot P) and Cc (slot Q) both dead

    // ---- MT[i][t] = M[t][i] (slot Q)  +  Xs[t][p] staging (slot P) ----
#pragma unroll
    for (int d = 0; d < 4; ++d)
        *(float4*)&MT[i4 + d][t4] = make_float4(m[0][d], m[1][d], m[2][d], m[3][d]);
    {   // X -> Xs[t][p]: conv+silu of x, this head's 64 channels
        const int ch = h * HEADDIM + sg * 4;
        float w[4][4], bb[4];
#pragma unroll
        for (int j = 0; j < 4; ++j) {
            bb[j] = b_conv[ch + j];
#pragma unroll
            for (int k = 0; k < 4; ++k) w[j][k] = W_conv[(ch + j) * 4 + k];
        }
        float rx[4][7];
#pragma unroll
        for (int r = 0; r < 7; ++r) {
            const int tg = tb + t4s - 3 + r;
            float4 v = make_float4(0.f, 0.f, 0.f, 0.f);
            if (tg >= 0) v = *(const float4*)(xbuf + (row0 + tg) * DINNER + ch);
            rx[0][r] = v.x; rx[1][r] = v.y; rx[2][r] = v.z; rx[3][r] = v.w;
        }
#pragma unroll
        for (int i = 0; i < 4; ++i) {
            float o[4];
#pragma unroll
            for (int j = 0; j < 4; ++j)
                o[j] = siluf(fmaf(rx[j][i + 3], w[j][3], fmaf(rx[j][i + 2], w[j][2],
                             fmaf(rx[j][i + 1], w[j][1], fmaf(rx[j][i], w[j][0], bb[j])))));
            *(float4*)&Xs[t4s + i][sg * 4] = make_float4(o[0], o[1], o[2], o[3]);
        }
    }
    __syncthreads();

    // ---- GEMM2: Yac[t][p] = M.X ----
    float yac[4][4];
#pragma unroll
    for (int a = 0; a < 4; ++a)
#pragma unroll
        for (int d = 0; d < 4; ++d) yac[a][d] = 0.f;
#pragma unroll 4
    for (int k = 0; k < CHUNK; ++k) {
        const float4 mv = *(const float4*)&MT[k][t4];
        const float4 xv = *(const float4*)&Xs[k][i4];
        const float ma[4] = {mv.x, mv.y, mv.z, mv.w};
        const float xa[4] = {xv.x, xv.y, xv.z, xv.w};
#pragma unroll
        for (int a = 0; a < 4; ++a)
#pragma unroll
            for (int d = 0; d < 4; ++d) yac[a][d] = fmaf(ma[a], xa[d], yac[a][d]);
    }

    // ---- epilogue: Y = Yac + a[t]*Y2 + D*X ; g = Y*silu(z) -> zbuf ----
#pragma unroll
    for (int a = 0; a < 4; ++a) {
        const int t = t4 + a;
        const float at = a_l[t];
        const float4 xv = *(const float4*)&Xs[t][i4];
        const float xa[4] = {xv.x, xv.y, xv.z, xv.w};
        float* zp = zbuf + (row0 + tb + t) * DINNER + h * HEADDIM + i4;
        const float4 zv = *(const float4*)zp;
        const float za[4] = {zv.x, zv.y, zv.z, zv.w};
        float g[4];
#pragma unroll
        for (int d = 0; d < 4; ++d) {
            const float Y = yac[a][d] + at * y2[a][d] + Dh * xa[d];
            g[d] = Y * siluf(za[d]);
        }
        *(float4*)zp = make_float4(g[0], g[1], g[2], g[3]);
    }
}

// ---------------------------------------------------------------------------
__launch_bounds__(256)
__global__ void rms_val(const float* __restrict__ g, const float* __restrict__ Wv,
                        const float* __restrict__ bval, float* __restrict__ values,
                        unsigned short* __restrict__ Ghi, unsigned short* __restrict__ Glo)
{
    const size_t tok = (size_t)blockIdx.x * 4 + (threadIdx.x >> 6);
    const int lane = threadIdx.x & 63;
    const float4 v = *(const float4*)(g + tok * DINNER + lane * 4);
    const float4 w = *(const float4*)(Wv + lane * 4);
    float ssq = v.x * v.x + v.y * v.y + v.z * v.z + v.w * v.w;
    float gw  = v.x * w.x + v.y * w.y + v.z * w.z + v.w * w.w;
#pragma unroll
    for (int d = 1; d < 64; d <<= 1) {
        ssq += __shfl_xor(ssq, d, 64);
        gw  += __shfl_xor(gw, d, 64);
    }
    const float rms = rsqrtf(ssq * (1.f / DINNER) + 1e-5f);
    u16x4 h, l;
    splitbf(v.x * rms, ((unsigned short*)&h)[0], ((unsigned short*)&l)[0]);
    splitbf(v.y * rms, ((unsigned short*)&h)[1], ((unsigned short*)&l)[1]);
    splitbf(v.z * rms, ((unsigned short*)&h)[2], ((unsigned short*)&l)[2]);
    splitbf(v.w * rms, ((unsigned short*)&h)[3], ((unsigned short*)&l)[3]);
    *(u16x4*)(Ghi + tok * DINNER + lane * 4) = h;
    *(u16x4*)(Glo + tok * DINNER + lane * 4) = l;
    if (lane == 0) values[tok] = gw * rms + bval[0];
}

// ---------------------------------------------------------------------------
extern "C" void kernel_launch(void* const* d_in, const int* in_sizes, int n_in,
                              void* d_out, int out_size, void* d_ws, size_t ws_size,
                              hipStream_t stream)
{
    (void)in_sizes; (void)n_in; (void)out_size; (void)ws_size;
    const float* obs     = (const float*)d_in[0];
    const float* W_enc   = (const float*)d_in[1];
    const float* b_enc   = (const float*)d_in[2];
    const float* W_in    = (const float*)d_in[3];
    const float* W_conv  = (const float*)d_in[4];
    const float* b_conv  = (const float*)d_in[5];
    const float* dt_bias = (const float*)d_in[6];
    const float* A_log   = (const float*)d_in[7];
    const float* Dp      = (const float*)d_in[8];
    const float* norm_w  = (const float*)d_in[9];
    const float* W_out   = (const float*)d_in[10];
    const float* W_act   = (const float*)d_in[11];
    const float* b_act   = (const float*)d_in[12];
    const float* W_val   = (const float*)d_in[13];
    const float* b_val   = (const float*)d_in[14];

    float* logits = (float*)d_out;
    float* values = logits + (size_t)NTOK * NACT;

    char* ws = (char*)d_ws;
    size_t off = 0;
    auto alloc = [&](size_t nbytes) {
        char* ptr = ws + off;
        off += (nbytes + 255) / 256 * 256;
        return ptr;
    };
    float* zbuf   = (float*)alloc((size_t)NTOK * DINNER * 4);   // z -> g in place
    float* xbuf   = (float*)alloc((size_t)NTOK * DINNER * 4);
    float* bcbuf  = (float*)alloc((size_t)NTOK * BCW2 * 4);
    float* dtcol  = (float*)alloc((size_t)NTOK * 4 * 4);
    // shared 134.2 MB region: states (scan) -> g-bf16 (rms_val/logits)
    char*  shared = alloc((size_t)NTOK * OBSD * 2 * 2);
    float* states = (float*)shared;
    unsigned short* Ghi = (unsigned short*)shared;
    unsigned short* Glo = Ghi + (size_t)NTOK * DINNER;
    float* dtT    = (float*)alloc((size_t)NBATCH * NHEADS * TSEQ * 4);
    float* laT    = (float*)alloc((size_t)NBATCH * NHEADS * TSEQ * 4);
    float* dApb   = (float*)alloc(NBATCH * NHEADS * NCHUNK * 4);
    unsigned short* WcThi = (unsigned short*)alloc((size_t)NPPAD * OBSD * 2);
    unsigned short* WcTlo = (unsigned short*)alloc((size_t)NPPAD * OBSD * 2);
    float* bz     = (float*)alloc(NPPAD * 4);
    unsigned short* WhThi = (unsigned short*)alloc((size_t)NACT * DINNER * 2);
    unsigned short* WhTlo = (unsigned short*)alloc((size_t)NACT * DINNER * 2);
    float* Wv     = (float*)alloc(DINNER * 4);

    fuse_whead<<<DINNER, NACT, 0, stream>>>(W_out, W_act, W_val, norm_w, WhThi, WhTlo, Wv);
    make_wc<<<NPPAD, 256, 0, stream>>>(W_enc, W_in, b_enc, WcThi, WcTlo, bz);
    // in_proj: A staged from fp32 obs, split in-register; XCD-swizzled grid
    mfma_gemm<1><<<dim3(NPPAD / 64, NTOK / 128), 256, 0, stream>>>(
        obs, nullptr, nullptr, WcThi, WcTlo, OBSD, bz, nullptr, zbuf, xbuf, bcbuf, dtcol);
    prep_scan<<<NBATCH * NHEADS * NCHUNK, 64, 0, stream>>>(
        dtcol, dt_bias, A_log, dtT, laT, dApb);
    scan_state<<<dim3(NCHUNK, NBATCH * NHEADS), 256, 0, stream>>>(
        xbuf, bcbuf, dtT, laT, W_conv, b_conv, states);
    chunk_scan<<<NBATCH * NHEADS * 16, 256, 0, stream>>>(states, dApb);
    scan_out<<<dim3(NCHUNK, NBATCH * NHEADS), 256, 0, stream>>>(
        xbuf, bcbuf, zbuf, dtT, laT, W_conv, b_conv, Dp, states);
    rms_val<<<NTOK / 4, 256, 0, stream>>>(zbuf, Wv, b_val, values, Ghi, Glo);
    mfma_gemm<0><<<dim3(1, NTOK / 128), 256, 0, stream>>>(
        nullptr, Ghi, Glo, WhThi, WhTlo, DINNER, b_act, logits, nullptr, nullptr, nullptr, nullptr);
}